// Round 1
// baseline (1093.430 us; speedup 1.0000x reference)
//
#include <hip/hip_runtime.h>
#include <hip/hip_bf16.h>

#define BF16 __hip_bfloat16
typedef short bf16x8 __attribute__((ext_vector_type(8)));
typedef float f32x4  __attribute__((ext_vector_type(4)));
typedef unsigned int u32;

#define MFMA16(a, b, c) __builtin_amdgcn_mfma_f32_16x16x32_bf16(a, b, c, 0, 0, 0)

// Sizes (compile-time constants for this problem)
// B=1, SV=2048, SA=512, S=2560, D=1024, H=16, DH=64, F=4096, L=2

__device__ __forceinline__ void async16(const void* g, void* l) {
  __builtin_amdgcn_global_load_lds(
      (const __attribute__((address_space(1))) u32*)g,
      (__attribute__((address_space(3))) u32*)l, 16, 0, 0);
}

// ---------------- weight transpose + f32->bf16 cast ----------------
// W: (nmat, K, N) f32 row-major -> WT: (nmat, N, K) bf16 row-major
__global__ __launch_bounds__(256) void wtrans(const float* __restrict__ W,
                                              BF16* __restrict__ WT, int K, int N) {
  __shared__ float t[32][33];
  const size_t msz = (size_t)K * N;
  const float* Wm = W + msz * blockIdx.z;
  BF16* Tm = WT + msz * blockIdx.z;
  int n0 = blockIdx.x * 32, k0 = blockIdx.y * 32;
  int tx = threadIdx.x & 31, ty = threadIdx.x >> 5;
#pragma unroll
  for (int i = 0; i < 4; i++)
    t[ty + 8 * i][tx] = Wm[(size_t)(k0 + ty + 8 * i) * N + n0 + tx];
  __syncthreads();
#pragma unroll
  for (int i = 0; i < 4; i++)
    Tm[(size_t)(n0 + ty + 8 * i) * K + k0 + tx] = __float2bfloat16(t[tx][ty + 8 * i]);
}

// ---------------- LayerNorm * (1+sc) + sh -> bf16 ----------------
__global__ __launch_bounds__(256) void ln_mod(const float* __restrict__ x,
                                              BF16* __restrict__ out,
                                              const float* __restrict__ mod,
                                              const float* __restrict__ tmv,
                                              const float* __restrict__ tma,
                                              int l, int ish, int isc) {
  int r = blockIdx.x;
  int e = (r >= 2048) ? 1 : 0;
  const float* tm = e ? tma : tmv;
  const float* mo = mod + (size_t)((e * 2 + l) * 6) * 1024;
  float4 v = ((const float4*)(x + (size_t)r * 1024))[threadIdx.x];
  float s = v.x + v.y + v.z + v.w;
  float s2 = v.x * v.x + v.y * v.y + v.z * v.z + v.w * v.w;
#pragma unroll
  for (int off = 32; off >= 1; off >>= 1) {
    s += __shfl_down(s, off);
    s2 += __shfl_down(s2, off);
  }
  __shared__ float red[8];
  int lane = threadIdx.x & 63, w = threadIdx.x >> 6;
  if (lane == 0) { red[w] = s; red[4 + w] = s2; }
  __syncthreads();
  s = red[0] + red[1] + red[2] + red[3];
  s2 = red[4] + red[5] + red[6] + red[7];
  float mu = s * (1.f / 1024.f);
  float var = s2 * (1.f / 1024.f) - mu * mu;
  float inv = rsqrtf(var + 1e-6f);
  int c = threadIdx.x * 4;
  BF16* o = out + (size_t)r * 1024 + c;
  float xv[4] = {v.x, v.y, v.z, v.w};
#pragma unroll
  for (int k = 0; k < 4; k++) {
    float sc = mo[isc * 1024 + c + k] + tm[isc * 1024 + c + k];
    float sh = mo[ish * 1024 + c + k] + tm[ish * 1024 + c + k];
    o[k] = __float2bfloat16((xv[k] - mu) * inv * (1.f + sc) + sh);
  }
}

// ---------------- RMSNorm + gain + RoPE for q/k -> (H,S,DH) bf16 ----------------
__global__ __launch_bounds__(256) void qk_post(const float* __restrict__ qraw,
                                               const float* __restrict__ kraw,
                                               const float* __restrict__ gq,
                                               const float* __restrict__ gk,
                                               BF16* __restrict__ Qb, BF16* __restrict__ Kb,
                                               const float* __restrict__ vfreq,
                                               const float* __restrict__ afreq, int l) {
  int r = blockIdx.x;
  int which = blockIdx.y;
  const float* src = (which ? kraw : qraw) + (size_t)r * 1024;
  int e = (r >= 2048) ? 1 : 0;
  const float* g = (which ? gk : gq) + (size_t)(e * 2 + l) * 1024;
  BF16* dst = which ? Kb : Qb;
  const float* fr = e ? (afreq + (size_t)(r - 2048) * 32) : (vfreq + (size_t)r * 32);
  float4 v = ((const float4*)src)[threadIdx.x];
  float s2 = v.x * v.x + v.y * v.y + v.z * v.z + v.w * v.w;
#pragma unroll
  for (int off = 32; off >= 1; off >>= 1) s2 += __shfl_down(s2, off);
  __shared__ float red[4];
  int lane = threadIdx.x & 63, w = threadIdx.x >> 6;
  if (lane == 0) red[w] = s2;
  __syncthreads();
  s2 = red[0] + red[1] + red[2] + red[3];
  float inv = rsqrtf(s2 * (1.f / 1024.f) + 1e-6f);
  int c = threadIdx.x * 4;
  float xe0 = v.x * inv * g[c], xo0 = v.y * inv * g[c + 1];
  float xe1 = v.z * inv * g[c + 2], xo1 = v.w * inv * g[c + 3];
  int p0 = (c & 63) >> 1;
  float c0, s0, c1, s1;
  sincosf(fr[p0], &s0, &c0);
  sincosf(fr[p0 + 1], &s1, &c1);
  int h = c >> 6;
  size_t o = ((size_t)h * 2560 + r) * 64 + (c & 63);
  dst[o + 0] = __float2bfloat16(xe0 * c0 - xo0 * s0);
  dst[o + 1] = __float2bfloat16(xe0 * s0 + xo0 * c0);
  dst[o + 2] = __float2bfloat16(xe1 * c1 - xo1 * s1);
  dst[o + 3] = __float2bfloat16(xe1 * s1 + xo1 * c1);
}

// ---------------- V (S,D) f32 -> V^T (H*DH, S) bf16 ----------------
__global__ __launch_bounds__(256) void vpost(const float* __restrict__ vraw,
                                             BF16* __restrict__ VT) {
  __shared__ float t[32][33];
  int r0 = blockIdx.x * 32, c0 = blockIdx.y * 32;
  int tx = threadIdx.x & 31, ty = threadIdx.x >> 5;
#pragma unroll
  for (int i = 0; i < 4; i++)
    t[ty + 8 * i][tx] = vraw[(size_t)(r0 + ty + 8 * i) * 1024 + c0 + tx];
  __syncthreads();
#pragma unroll
  for (int i = 0; i < 4; i++)
    VT[(size_t)(c0 + ty + 8 * i) * 2560 + r0 + tx] = __float2bfloat16(t[tx][ty + 8 * i]);
}

// ---------------- generic grouped GEMM: C = A(MxK) * B^T(NxK) + bias ----------------
// EPI: 0 = f32 out (bias only), 1 = gelu -> bf16 out, 2 = xout = xin + (g1+g2)*val (f32)
struct GDesc {
  const BF16* A; const BF16* B; const float* bias;
  void* out; const float* xin; float* xout; const float* g1; const float* g2; int M;
};
template <int NZ> struct GPack { GDesc d[NZ]; };

template <int EPI, int NZ>
__global__ __launch_bounds__(256) void gemm_bt(GPack<NZ> P, int N, int K) {
  GDesc dd = P.d[blockIdx.z];
  int m0 = blockIdx.x * 128;
  if (m0 >= dd.M) return;
  int n0 = blockIdx.y * 128;
  __shared__ BF16 As[128 * 32];
  __shared__ BF16 Bs[128 * 32];
  int tid = threadIdx.x, lane = tid & 63, w = tid >> 6;
  int wr = w & 1, wc = w >> 1;
  const BF16* Ab = dd.A + (size_t)m0 * K;
  const BF16* Bb = dd.B + (size_t)n0 * K;
  int ob0 = (w * 2 + 0) * 1024 + lane * 16;  // byte offset in 8KB tile
  int ob1 = (w * 2 + 1) * 1024 + lane * 16;
  int ar0 = ob0 >> 6, ac0 = (ob0 & 63) >> 1;
  int ar1 = ob1 >> 6, ac1 = (ob1 & 63) >> 1;
  int m15 = lane & 15, q4 = lane >> 4;
  int fr = m15 * 32 + q4 * 8;
  f32x4 acc[4][4] = {};
  for (int k0 = 0; k0 < K; k0 += 32) {
    __syncthreads();
    async16(Ab + (size_t)ar0 * K + k0 + ac0, &As[(w * 2 + 0) * 512]);
    async16(Ab + (size_t)ar1 * K + k0 + ac1, &As[(w * 2 + 1) * 512]);
    async16(Bb + (size_t)ar0 * K + k0 + ac0, &Bs[(w * 2 + 0) * 512]);
    async16(Bb + (size_t)ar1 * K + k0 + ac1, &Bs[(w * 2 + 1) * 512]);
    __syncthreads();
    bf16x8 af[4], bv[4];
#pragma unroll
    for (int i = 0; i < 4; i++) af[i] = *(const bf16x8*)&As[(wr * 64 + 16 * i) * 32 + fr];
#pragma unroll
    for (int j = 0; j < 4; j++) bv[j] = *(const bf16x8*)&Bs[(wc * 64 + 16 * j) * 32 + fr];
#pragma unroll
    for (int i = 0; i < 4; i++)
#pragma unroll
      for (int j = 0; j < 4; j++)
        acc[i][j] = MFMA16(af[i], bv[j], acc[i][j]);
  }
#pragma unroll
  for (int i = 0; i < 4; i++) {
    int row = m0 + wr * 64 + 16 * i + q4 * 4;
#pragma unroll
    for (int j = 0; j < 4; j++) {
      int col = n0 + wc * 64 + 16 * j + m15;
      float b = dd.bias[col];
#pragma unroll
      for (int rg = 0; rg < 4; rg++) {
        float v = acc[i][j][rg] + b;
        size_t idx = (size_t)(row + rg) * N + col;
        if (EPI == 0) {
          ((float*)dd.out)[idx] = v;
        } else if (EPI == 1) {
          float u = 0.7978845608f * (v + 0.044715f * v * v * v);
          ((BF16*)dd.out)[idx] = __float2bfloat16(0.5f * v * (1.f + tanhf(u)));
        } else {
          float gv = dd.g1[col] + dd.g2[col];
          dd.xout[idx] = dd.xin[idx] + gv * v;
        }
      }
    }
  }
}

// ---------------- flash attention ----------------
// Qb,Kb: (H,S,DH) bf16; VT: (H,DH,S) bf16; O: (S, H*DH) bf16
__global__ __launch_bounds__(256) void flash(const BF16* __restrict__ Qb,
                                             const BF16* __restrict__ Kb,
                                             const BF16* __restrict__ VT,
                                             BF16* __restrict__ O) {
  const int S = 2560, SV = 2048;
  __shared__ BF16 Qs[64 * 64], Ks[64 * 64], Vs[64 * 64];
  __shared__ BF16 Ps[4][16 * 64];
  int tid = threadIdx.x, lane = tid & 63, w = tid >> 6;
  int h = blockIdx.y, q0 = blockIdx.x * 64;
  int m15 = lane & 15, q4 = lane >> 4;
  {
    const BF16* g = Qb + ((size_t)h * S + q0) * 64;
    async16(g + (w * 2 + 0) * 512 + lane * 8, &Qs[(w * 2 + 0) * 512]);
    async16(g + (w * 2 + 1) * 512 + lane * 8, &Qs[(w * 2 + 1) * 512]);
  }
  __syncthreads();
  bf16x8 qf[2];
  qf[0] = *(const bf16x8*)&Qs[(w * 16 + m15) * 64 + q4 * 8];
  qf[1] = *(const bf16x8*)&Qs[(w * 16 + m15) * 64 + 32 + q4 * 8];
  f32x4 oa[4] = {};
  float m_i[4] = {-1e30f, -1e30f, -1e30f, -1e30f};
  float l_i[4] = {0.f, 0.f, 0.f, 0.f};
  int actq = (q0 >= SV);
  int nt = actq ? (33 + ((q0 - SV) >> 6)) : 32;
  for (int t = 0; t < nt; t++) {
    __syncthreads();
    {
      const BF16* kg = Kb + ((size_t)h * S + t * 64) * 64;
      async16(kg + (w * 2 + 0) * 512 + lane * 8, &Ks[(w * 2 + 0) * 512]);
      async16(kg + (w * 2 + 1) * 512 + lane * 8, &Ks[(w * 2 + 1) * 512]);
      int d0 = (w * 2 + 0) * 8 + (lane >> 3);
      const BF16* vg = VT + (size_t)(h * 64) * S + t * 64 + (lane & 7) * 8;
      async16(vg + (size_t)d0 * S, &Vs[(w * 2 + 0) * 512]);
      async16(vg + (size_t)(d0 + 8) * S, &Vs[(w * 2 + 1) * 512]);
    }
    __syncthreads();
    f32x4 sa[4];
#pragma unroll
    for (int j = 0; j < 4; j++) {
      bf16x8 k0f = *(const bf16x8*)&Ks[(j * 16 + m15) * 64 + q4 * 8];
      bf16x8 k1f = *(const bf16x8*)&Ks[(j * 16 + m15) * 64 + 32 + q4 * 8];
      f32x4 z = {};
      z = MFMA16(qf[0], k0f, z);
      sa[j] = MFMA16(qf[1], k1f, z);
    }
    float sv[4][4];
    bool diag = actq && (t == nt - 1);
#pragma unroll
    for (int j = 0; j < 4; j++)
#pragma unroll
      for (int rg = 0; rg < 4; rg++) {
        float vv = sa[j][rg] * 0.125f;
        if (diag) {
          int rowg = q0 + w * 16 + q4 * 4 + rg;
          int colg = t * 64 + j * 16 + m15;
          if (colg > rowg) vv = -1e9f;
        }
        sv[j][rg] = vv;
      }
    float mn[4], al[4], rs[4];
#pragma unroll
    for (int rg = 0; rg < 4; rg++) {
      float mx = fmaxf(fmaxf(sv[0][rg], sv[1][rg]), fmaxf(sv[2][rg], sv[3][rg]));
      mx = fmaxf(mx, __shfl_xor(mx, 1));
      mx = fmaxf(mx, __shfl_xor(mx, 2));
      mx = fmaxf(mx, __shfl_xor(mx, 4));
      mx = fmaxf(mx, __shfl_xor(mx, 8));
      mn[rg] = fmaxf(m_i[rg], mx);
      al[rg] = __expf(m_i[rg] - mn[rg]);
      m_i[rg] = mn[rg];
      rs[rg] = 0.f;
    }
#pragma unroll
    for (int j = 0; j < 4; j++)
#pragma unroll
      for (int rg = 0; rg < 4; rg++) {
        float p = __expf(sv[j][rg] - mn[rg]);
        rs[rg] += p;
        Ps[w][(q4 * 4 + rg) * 64 + j * 16 + m15] = __float2bfloat16(p);
      }
#pragma unroll
    for (int rg = 0; rg < 4; rg++) {
      float r = rs[rg];
      r += __shfl_xor(r, 1);
      r += __shfl_xor(r, 2);
      r += __shfl_xor(r, 4);
      r += __shfl_xor(r, 8);
      l_i[rg] = l_i[rg] * al[rg] + r;
    }
#pragma unroll
    for (int jb = 0; jb < 4; jb++)
#pragma unroll
      for (int rg = 0; rg < 4; rg++) oa[jb][rg] *= al[rg];
#pragma unroll
    for (int s = 0; s < 2; s++) {
      bf16x8 pf = *(const bf16x8*)&Ps[w][m15 * 64 + s * 32 + q4 * 8];
#pragma unroll
      for (int jb = 0; jb < 4; jb++) {
        bf16x8 vf = *(const bf16x8*)&Vs[(jb * 16 + m15) * 64 + s * 32 + q4 * 8];
        oa[jb] = MFMA16(pf, vf, oa[jb]);
      }
    }
  }
#pragma unroll
  for (int jb = 0; jb < 4; jb++)
#pragma unroll
    for (int rg = 0; rg < 4; rg++) {
      int row = q0 + w * 16 + q4 * 4 + rg;
      int col = h * 64 + jb * 16 + m15;
      O[(size_t)row * 1024 + col] = __float2bfloat16(oa[jb][rg] / l_i[rg]);
    }
}

// ---------------- host ----------------
extern "C" void kernel_launch(void* const* d_in, const int* in_sizes, int n_in,
                              void* d_out, int out_size, void* d_ws, size_t ws_size,
                              hipStream_t stream) {
  (void)in_sizes; (void)n_in; (void)out_size; (void)ws_size;
  const float* vid  = (const float*)d_in[0];
  const float* act  = (const float*)d_in[1];
  const float* vfr  = (const float*)d_in[2];
  const float* afr  = (const float*)d_in[3];
  const float* tmv  = (const float*)d_in[4];
  const float* tma  = (const float*)d_in[5];
  const float* Wq   = (const float*)d_in[6];
  const float* Wk   = (const float*)d_in[7];
  const float* Wv   = (const float*)d_in[8];
  const float* Wo   = (const float*)d_in[9];
  const float* bq   = (const float*)d_in[10];
  const float* bk   = (const float*)d_in[11];
  const float* bv   = (const float*)d_in[12];
  const float* bo   = (const float*)d_in[13];
  const float* gq   = (const float*)d_in[14];
  const float* gk   = (const float*)d_in[15];
  const float* modp = (const float*)d_in[16];
  const float* W1   = (const float*)d_in[17];
  const float* b1   = (const float*)d_in[18];
  const float* W2   = (const float*)d_in[19];
  const float* b2   = (const float*)d_in[20];

  char* p = (char*)d_ws;
  auto carve = [&](size_t bytes) {
    char* r = p;
    p += (bytes + 255) & ~(size_t)255;
    return r;
  };
  BF16* WqT = (BF16*)carve(4ull * 1024 * 1024 * 2);
  BF16* WkT = (BF16*)carve(4ull * 1024 * 1024 * 2);
  BF16* WvT = (BF16*)carve(4ull * 1024 * 1024 * 2);
  BF16* WoT = (BF16*)carve(4ull * 1024 * 1024 * 2);
  BF16* W1T = (BF16*)carve(16ull * 1024 * 1024 * 2);
  BF16* W2T = (BF16*)carve(16ull * 1024 * 1024 * 2);
  float* x    = (float*)carve(2560ull * 1024 * 4);
  BF16* abf   = (BF16*)carve(2560ull * 1024 * 2);
  float* qraw = (float*)carve(2560ull * 1024 * 4);
  float* kraw = (float*)carve(2560ull * 1024 * 4);
  float* vraw = (float*)carve(2560ull * 1024 * 4);
  BF16* Qb    = (BF16*)carve(2560ull * 1024 * 2);
  BF16* Kb    = (BF16*)carve(2560ull * 1024 * 2);
  BF16* VTb   = (BF16*)carve(2560ull * 1024 * 2);
  BF16* Obf   = (BF16*)carve(2560ull * 1024 * 2);
  BF16* mibf  = (BF16*)carve(2560ull * 1024 * 2);
  BF16* hbf   = (BF16*)carve(2560ull * 4096 * 2);

  hipMemcpyAsync(x, vid, 2048ull * 1024 * 4, hipMemcpyDeviceToDevice, stream);
  hipMemcpyAsync(x + 2048ull * 1024, act, 512ull * 1024 * 4, hipMemcpyDeviceToDevice, stream);

  wtrans<<<dim3(32, 32, 4), 256, 0, stream>>>(Wq, WqT, 1024, 1024);
  wtrans<<<dim3(32, 32, 4), 256, 0, stream>>>(Wk, WkT, 1024, 1024);
  wtrans<<<dim3(32, 32, 4), 256, 0, stream>>>(Wv, WvT, 1024, 1024);
  wtrans<<<dim3(32, 32, 4), 256, 0, stream>>>(Wo, WoT, 1024, 1024);
  wtrans<<<dim3(128, 32, 4), 256, 0, stream>>>(W1, W1T, 1024, 4096);
  wtrans<<<dim3(32, 128, 4), 256, 0, stream>>>(W2, W2T, 4096, 1024);

  for (int l = 0; l < 2; l++) {
    ln_mod<<<2560, 256, 0, stream>>>(x, abf, modp, tmv, tma, l, 0, 1);
    {
      GPack<6> pk;
      for (int e = 0; e < 2; e++)
        for (int t = 0; t < 3; t++) {
          GDesc& dd = pk.d[e * 3 + t];
          dd.A = abf + (size_t)e * 2048 * 1024;
          dd.B = (t == 0 ? WqT : t == 1 ? WkT : WvT) + (size_t)(e * 2 + l) * 1024 * 1024;
          dd.bias = (t == 0 ? bq : t == 1 ? bk : bv) + (size_t)(e * 2 + l) * 1024;
          dd.out = (t == 0 ? qraw : t == 1 ? kraw : vraw) + (size_t)e * 2048 * 1024;
          dd.xin = nullptr; dd.xout = nullptr; dd.g1 = nullptr; dd.g2 = nullptr;
          dd.M = e ? 512 : 2048;
        }
      gemm_bt<0, 6><<<dim3(16, 8, 6), 256, 0, stream>>>(pk, 1024, 1024);
    }
    qk_post<<<dim3(2560, 2), 256, 0, stream>>>(qraw, kraw, gq, gk, Qb, Kb, vfr, afr, l);
    vpost<<<dim3(80, 32), 256, 0, stream>>>(vraw, VTb);
    flash<<<dim3(40, 16), 256, 0, stream>>>(Qb, Kb, VTb, Obf);
    {
      GPack<2> pk;
      for (int e = 0; e < 2; e++) {
        GDesc& dd = pk.d[e];
        dd.A = Obf + (size_t)e * 2048 * 1024;
        dd.B = WoT + (size_t)(e * 2 + l) * 1024 * 1024;
        dd.bias = bo + (size_t)(e * 2 + l) * 1024;
        dd.out = nullptr;
        dd.xin = x + (size_t)e * 2048 * 1024;
        dd.xout = x + (size_t)e * 2048 * 1024;
        dd.g1 = modp + (size_t)((e * 2 + l) * 6 + 2) * 1024;
        dd.g2 = (e ? tma : tmv) + 2 * 1024;
        dd.M = e ? 512 : 2048;
      }
      gemm_bt<2, 2><<<dim3(16, 8, 2), 256, 0, stream>>>(pk, 1024, 1024);
    }
    ln_mod<<<2560, 256, 0, stream>>>(x, mibf, modp, tmv, tma, l, 3, 4);
    {
      GPack<2> pk;
      for (int e = 0; e < 2; e++) {
        GDesc& dd = pk.d[e];
        dd.A = mibf + (size_t)e * 2048 * 1024;
        dd.B = W1T + (size_t)(e * 2 + l) * 4096 * 1024;
        dd.bias = b1 + (size_t)(e * 2 + l) * 4096;
        dd.out = hbf + (size_t)e * 2048 * 4096;
        dd.xin = nullptr; dd.xout = nullptr; dd.g1 = nullptr; dd.g2 = nullptr;
        dd.M = e ? 512 : 2048;
      }
      gemm_bt<1, 2><<<dim3(16, 32, 2), 256, 0, stream>>>(pk, 4096, 1024);
    }
    {
      GPack<2> pk;
      for (int e = 0; e < 2; e++) {
        GDesc& dd = pk.d[e];
        dd.A = hbf + (size_t)e * 2048 * 4096;
        dd.B = W2T + (size_t)(e * 2 + l) * 4096 * 1024;
        dd.bias = b2 + (size_t)(e * 2 + l) * 1024;
        dd.out = nullptr;
        dd.xin = x + (size_t)e * 2048 * 1024;
        dd.xout = ((l == 1) ? (float*)d_out : x) + (size_t)e * 2048 * 1024;
        dd.g1 = modp + (size_t)((e * 2 + l) * 6 + 5) * 1024;
        dd.g2 = (e ? tma : tmv) + 5 * 1024;
        dd.M = e ? 512 : 2048;
      }
      gemm_bt<2, 2><<<dim3(16, 8, 2), 256, 0, stream>>>(pk, 1024, 4096);
    }
  }
}

// Round 2
// 1046.458 us; speedup vs baseline: 1.0449x; 1.0449x over previous
//
#include <hip/hip_runtime.h>
#include <hip/hip_bf16.h>

#define BF16 __hip_bfloat16
typedef short bf16x8 __attribute__((ext_vector_type(8)));
typedef float f32x4  __attribute__((ext_vector_type(4)));
typedef unsigned int u32;

#define MFMA16(a, b, c) __builtin_amdgcn_mfma_f32_16x16x32_bf16(a, b, c, 0, 0, 0)

// B=1, SV=2048, SA=512, S=2560, D=1024, H=16, DH=64, F=4096, L=2

__device__ __forceinline__ void async16(const void* g, void* l) {
  __builtin_amdgcn_global_load_lds(
      (const __attribute__((address_space(1))) u32*)g,
      (__attribute__((address_space(3))) u32*)l, 16, 0, 0);
}

// ---------------- weight transpose + f32->bf16 cast ----------------
__global__ __launch_bounds__(256) void wtrans(const float* __restrict__ W,
                                              BF16* __restrict__ WT, int K, int N) {
  __shared__ float t[32][33];
  const size_t msz = (size_t)K * N;
  const float* Wm = W + msz * blockIdx.z;
  BF16* Tm = WT + msz * blockIdx.z;
  int n0 = blockIdx.x * 32, k0 = blockIdx.y * 32;
  int tx = threadIdx.x & 31, ty = threadIdx.x >> 5;
#pragma unroll
  for (int i = 0; i < 4; i++)
    t[ty + 8 * i][tx] = Wm[(size_t)(k0 + ty + 8 * i) * N + n0 + tx];
  __syncthreads();
#pragma unroll
  for (int i = 0; i < 4; i++)
    Tm[(size_t)(n0 + ty + 8 * i) * K + k0 + tx] = __float2bfloat16(t[tx][ty + 8 * i]);
}

// ---------------- LayerNorm * (1+sc) + sh -> bf16 ----------------
__global__ __launch_bounds__(256) void ln_mod(const float* __restrict__ x,
                                              BF16* __restrict__ out,
                                              const float* __restrict__ mod,
                                              const float* __restrict__ tmv,
                                              const float* __restrict__ tma,
                                              int l, int ish, int isc) {
  int r = blockIdx.x;
  int e = (r >= 2048) ? 1 : 0;
  const float* tm = e ? tma : tmv;
  const float* mo = mod + (size_t)((e * 2 + l) * 6) * 1024;
  float4 v = ((const float4*)(x + (size_t)r * 1024))[threadIdx.x];
  float s = v.x + v.y + v.z + v.w;
  float s2 = v.x * v.x + v.y * v.y + v.z * v.z + v.w * v.w;
#pragma unroll
  for (int off = 32; off >= 1; off >>= 1) {
    s += __shfl_down(s, off);
    s2 += __shfl_down(s2, off);
  }
  __shared__ float red[8];
  int lane = threadIdx.x & 63, w = threadIdx.x >> 6;
  if (lane == 0) { red[w] = s; red[4 + w] = s2; }
  __syncthreads();
  s = red[0] + red[1] + red[2] + red[3];
  s2 = red[4] + red[5] + red[6] + red[7];
  float mu = s * (1.f / 1024.f);
  float var = s2 * (1.f / 1024.f) - mu * mu;
  float inv = rsqrtf(var + 1e-6f);
  int c = threadIdx.x * 4;
  BF16* o = out + (size_t)r * 1024 + c;
  float xv[4] = {v.x, v.y, v.z, v.w};
#pragma unroll
  for (int k = 0; k < 4; k++) {
    float sc = mo[isc * 1024 + c + k] + tm[isc * 1024 + c + k];
    float sh = mo[ish * 1024 + c + k] + tm[ish * 1024 + c + k];
    o[k] = __float2bfloat16((xv[k] - mu) * inv * (1.f + sc) + sh);
  }
}

// ---------------- RMSNorm + gain + RoPE for q/k -> (H,S,DH) bf16 ----------------
__global__ __launch_bounds__(256) void qk_post(const float* __restrict__ qraw,
                                               const float* __restrict__ kraw,
                                               const float* __restrict__ gq,
                                               const float* __restrict__ gk,
                                               BF16* __restrict__ Qb, BF16* __restrict__ Kb,
                                               const float* __restrict__ vfreq,
                                               const float* __restrict__ afreq, int l) {
  int r = blockIdx.x;
  int which = blockIdx.y;
  const float* src = (which ? kraw : qraw) + (size_t)r * 1024;
  int e = (r >= 2048) ? 1 : 0;
  const float* g = (which ? gk : gq) + (size_t)(e * 2 + l) * 1024;
  BF16* dst = which ? Kb : Qb;
  const float* fr = e ? (afreq + (size_t)(r - 2048) * 32) : (vfreq + (size_t)r * 32);
  float4 v = ((const float4*)src)[threadIdx.x];
  float s2 = v.x * v.x + v.y * v.y + v.z * v.z + v.w * v.w;
#pragma unroll
  for (int off = 32; off >= 1; off >>= 1) s2 += __shfl_down(s2, off);
  __shared__ float red[4];
  int lane = threadIdx.x & 63, w = threadIdx.x >> 6;
  if (lane == 0) red[w] = s2;
  __syncthreads();
  s2 = red[0] + red[1] + red[2] + red[3];
  float inv = rsqrtf(s2 * (1.f / 1024.f) + 1e-6f);
  int c = threadIdx.x * 4;
  float xe0 = v.x * inv * g[c], xo0 = v.y * inv * g[c + 1];
  float xe1 = v.z * inv * g[c + 2], xo1 = v.w * inv * g[c + 3];
  int p0 = (c & 63) >> 1;
  float c0, s0, c1, s1;
  sincosf(fr[p0], &s0, &c0);
  sincosf(fr[p0 + 1], &s1, &c1);
  int h = c >> 6;
  size_t o = ((size_t)h * 2560 + r) * 64 + (c & 63);
  dst[o + 0] = __float2bfloat16(xe0 * c0 - xo0 * s0);
  dst[o + 1] = __float2bfloat16(xe0 * s0 + xo0 * c0);
  dst[o + 2] = __float2bfloat16(xe1 * c1 - xo1 * s1);
  dst[o + 3] = __float2bfloat16(xe1 * s1 + xo1 * c1);
}

// ---------------- V (S,D) f32 -> V^T (H*DH, S) bf16 ----------------
__global__ __launch_bounds__(256) void vpost(const float* __restrict__ vraw,
                                             BF16* __restrict__ VT) {
  __shared__ float t[32][33];
  int r0 = blockIdx.x * 32, c0 = blockIdx.y * 32;
  int tx = threadIdx.x & 31, ty = threadIdx.x >> 5;
#pragma unroll
  for (int i = 0; i < 4; i++)
    t[ty + 8 * i][tx] = vraw[(size_t)(r0 + ty + 8 * i) * 1024 + c0 + tx];
  __syncthreads();
#pragma unroll
  for (int i = 0; i < 4; i++)
    VT[(size_t)(c0 + ty + 8 * i) * 2560 + r0 + tx] = __float2bfloat16(t[tx][ty + 8 * i]);
}

// ---------------- generic grouped GEMM: C = A(MxK) * B^T(NxK) + bias ----------------
// LDS tile: 128 rows x 32 bf16 (4 chunks of 16B per row), XOR-swizzled:
// LDS chunk (r, cc) holds logical chunk cc ^ ((r>>1)&3)  -> 2-way bank conflicts max.
struct GDesc {
  const BF16* A; const BF16* B; const float* bias;
  void* out; const float* xin; float* xout; const float* g1; const float* g2; int M;
};
template <int NZ> struct GPack { GDesc d[NZ]; };

template <int EPI, int NZ>
__global__ __launch_bounds__(256) void gemm_bt(GPack<NZ> P, int N, int K) {
  GDesc dd = P.d[blockIdx.z];
  int m0 = blockIdx.x * 128;
  if (m0 >= dd.M) return;
  int n0 = blockIdx.y * 128;
  __shared__ BF16 As[128 * 32];
  __shared__ BF16 Bs[128 * 32];
  int tid = threadIdx.x, lane = tid & 63, w = tid >> 6;
  int wr = w & 1, wc = w >> 1;
  const BF16* Ab = dd.A + (size_t)m0 * K;
  const BF16* Bb = dd.B + (size_t)n0 * K;
  int idx0 = (w * 2 + 0) * 64 + lane;
  int idx1 = idx0 + 64;
  int ar0 = idx0 >> 2, lc0 = (idx0 & 3) ^ ((ar0 >> 1) & 3);
  int ar1 = idx1 >> 2, lc1 = (idx1 & 3) ^ ((ar1 >> 1) & 3);
  int m15 = lane & 15, q4 = lane >> 4;
  int fr = m15 * 32 + (q4 ^ ((m15 >> 1) & 3)) * 8;  // swizzled fragment offset
  f32x4 acc[4][4] = {};
  for (int k0 = 0; k0 < K; k0 += 32) {
    __syncthreads();
    async16(Ab + (size_t)ar0 * K + k0 + lc0 * 8, &As[(w * 2 + 0) * 512]);
    async16(Ab + (size_t)ar1 * K + k0 + lc1 * 8, &As[(w * 2 + 1) * 512]);
    async16(Bb + (size_t)ar0 * K + k0 + lc0 * 8, &Bs[(w * 2 + 0) * 512]);
    async16(Bb + (size_t)ar1 * K + k0 + lc1 * 8, &Bs[(w * 2 + 1) * 512]);
    __syncthreads();
    bf16x8 af[4], bv[4];
#pragma unroll
    for (int i = 0; i < 4; i++) af[i] = *(const bf16x8*)&As[(wr * 64 + 16 * i) * 32 + fr];
#pragma unroll
    for (int j = 0; j < 4; j++) bv[j] = *(const bf16x8*)&Bs[(wc * 64 + 16 * j) * 32 + fr];
#pragma unroll
    for (int i = 0; i < 4; i++)
#pragma unroll
      for (int j = 0; j < 4; j++)
        acc[i][j] = MFMA16(af[i], bv[j], acc[i][j]);
  }
#pragma unroll
  for (int i = 0; i < 4; i++) {
    int row = m0 + wr * 64 + 16 * i + q4 * 4;
#pragma unroll
    for (int j = 0; j < 4; j++) {
      int col = n0 + wc * 64 + 16 * j + m15;
      float b = dd.bias[col];
#pragma unroll
      for (int rg = 0; rg < 4; rg++) {
        float v = acc[i][j][rg] + b;
        size_t idx = (size_t)(row + rg) * N + col;
        if (EPI == 0) {
          ((float*)dd.out)[idx] = v;
        } else if (EPI == 1) {
          float u = 0.7978845608f * (v + 0.044715f * v * v * v);
          ((BF16*)dd.out)[idx] = __float2bfloat16(0.5f * v * (1.f + tanhf(u)));
        } else {
          float gv = dd.g1[col] + dd.g2[col];
          dd.xout[idx] = dd.xin[idx] + gv * v;
        }
      }
    }
  }
}

// ---------------- flash attention (double-buffered, swizzled LDS) ----------------
// Qb,Kb: (H,S,DH) bf16; VT: (H,DH,S) bf16; O: (S, H*DH) bf16
// 64x64 tiles, row = 8 chunks of 16B, LDS chunk (r,cc) holds logical chunk cc^(r&7).
__global__ __launch_bounds__(256) void flash(const BF16* __restrict__ Qb,
                                             const BF16* __restrict__ Kb,
                                             const BF16* __restrict__ VT,
                                             BF16* __restrict__ O) {
  const int S = 2560, SV = 2048;
  __shared__ BF16 Qs[64 * 64];
  __shared__ BF16 Ks[2][64 * 64];
  __shared__ BF16 Vs[2][64 * 64];
  __shared__ BF16 Ps[4][16 * 72];  // padded stride 72 -> 2-way max
  int tid = threadIdx.x, lane = tid & 63, w = tid >> 6;
  int h = blockIdx.y, q0 = blockIdx.x * 64;
  int m15 = lane & 15, q4 = lane >> 4;
  // staging lane mapping (swizzled): chunk idx -> (row, lds-chunk) -> logical chunk
  int idx0 = (w * 2 + 0) * 64 + lane, idx1 = idx0 + 64;
  int r0 = idx0 >> 3, c0 = (idx0 & 7) ^ (r0 & 7);
  int r1 = idx1 >> 3, c1 = (idx1 & 7) ^ (r1 & 7);

  const BF16* kbase = Kb + (size_t)h * S * 64;
  const BF16* vbase = VT + (size_t)h * 64 * S;
  {
    const BF16* qg = Qb + ((size_t)h * S + q0) * 64;
    async16(qg + r0 * 64 + c0 * 8, &Qs[(w * 2 + 0) * 512]);
    async16(qg + r1 * 64 + c1 * 8, &Qs[(w * 2 + 1) * 512]);
  }
  int actq = (q0 >= SV);
  int nt = actq ? (33 + ((q0 - SV) >> 6)) : 32;
  // stage K/V tile 0 into buffer 0
  {
    const BF16* kg = kbase;
    const BF16* vg = vbase;
    async16(kg + r0 * 64 + c0 * 8, &Ks[0][(w * 2 + 0) * 512]);
    async16(kg + r1 * 64 + c1 * 8, &Ks[0][(w * 2 + 1) * 512]);
    async16(vg + (size_t)r0 * S + c0 * 8, &Vs[0][(w * 2 + 0) * 512]);
    async16(vg + (size_t)r1 * S + c1 * 8, &Vs[0][(w * 2 + 1) * 512]);
  }
  __syncthreads();
  bf16x8 qf[2];
  {
    int rr = w * 16 + m15;
    qf[0] = *(const bf16x8*)&Qs[rr * 64 + ((q4) ^ (m15 & 7)) * 8];
    qf[1] = *(const bf16x8*)&Qs[rr * 64 + ((4 + q4) ^ (m15 & 7)) * 8];
  }
  f32x4 oa[4] = {};
  float m_i[4] = {-1e30f, -1e30f, -1e30f, -1e30f};
  float l_i[4] = {0.f, 0.f, 0.f, 0.f};
  const float SC2 = 0.125f * 1.44269504f;  // base-2 softmax scale
  for (int t = 0; t < nt; t++) {
    int cur = t & 1;
    if (t + 1 < nt) {  // prefetch next tile; vmcnt drains at end-of-iter barrier
      int nb = cur ^ 1;
      const BF16* kg = kbase + (size_t)(t + 1) * 64 * 64;
      const BF16* vg = vbase + (t + 1) * 64;
      async16(kg + r0 * 64 + c0 * 8, &Ks[nb][(w * 2 + 0) * 512]);
      async16(kg + r1 * 64 + c1 * 8, &Ks[nb][(w * 2 + 1) * 512]);
      async16(vg + (size_t)r0 * S + c0 * 8, &Vs[nb][(w * 2 + 0) * 512]);
      async16(vg + (size_t)r1 * S + c1 * 8, &Vs[nb][(w * 2 + 1) * 512]);
    }
    f32x4 sa[4];
#pragma unroll
    for (int j = 0; j < 4; j++) {
      int rr = j * 16 + m15;
      bf16x8 k0f = *(const bf16x8*)&Ks[cur][rr * 64 + ((q4) ^ (m15 & 7)) * 8];
      bf16x8 k1f = *(const bf16x8*)&Ks[cur][rr * 64 + ((4 + q4) ^ (m15 & 7)) * 8];
      f32x4 z = {};
      z = MFMA16(qf[0], k0f, z);
      sa[j] = MFMA16(qf[1], k1f, z);
    }
    float sv[4][4];
    bool diag = actq && (t == nt - 1);
#pragma unroll
    for (int j = 0; j < 4; j++)
#pragma unroll
      for (int rg = 0; rg < 4; rg++) {
        float vv = sa[j][rg] * SC2;
        if (diag) {
          int rowg = q0 + w * 16 + q4 * 4 + rg;
          int colg = t * 64 + j * 16 + m15;
          if (colg > rowg) vv = -1e9f;
        }
        sv[j][rg] = vv;
      }
    float mn[4], al[4], rs[4];
#pragma unroll
    for (int rg = 0; rg < 4; rg++) {
      float mx = fmaxf(fmaxf(sv[0][rg], sv[1][rg]), fmaxf(sv[2][rg], sv[3][rg]));
      mx = fmaxf(mx, __shfl_xor(mx, 1));
      mx = fmaxf(mx, __shfl_xor(mx, 2));
      mx = fmaxf(mx, __shfl_xor(mx, 4));
      mx = fmaxf(mx, __shfl_xor(mx, 8));
      mn[rg] = fmaxf(m_i[rg], mx);
      al[rg] = exp2f(m_i[rg] - mn[rg]);
      m_i[rg] = mn[rg];
      rs[rg] = 0.f;
    }
#pragma unroll
    for (int j = 0; j < 4; j++)
#pragma unroll
      for (int rg = 0; rg < 4; rg++) {
        float p = exp2f(sv[j][rg] - mn[rg]);
        rs[rg] += p;
        Ps[w][(q4 * 4 + rg) * 72 + j * 16 + m15] = __float2bfloat16(p);
      }
#pragma unroll
    for (int rg = 0; rg < 4; rg++) {
      float r = rs[rg];
      r += __shfl_xor(r, 1);
      r += __shfl_xor(r, 2);
      r += __shfl_xor(r, 4);
      r += __shfl_xor(r, 8);
      l_i[rg] = l_i[rg] * al[rg] + r;
    }
#pragma unroll
    for (int jb = 0; jb < 4; jb++)
#pragma unroll
      for (int rg = 0; rg < 4; rg++) oa[jb][rg] *= al[rg];
#pragma unroll
    for (int s = 0; s < 2; s++) {
      bf16x8 pf = *(const bf16x8*)&Ps[w][m15 * 72 + s * 32 + q4 * 8];
#pragma unroll
      for (int jb = 0; jb < 4; jb++) {
        int rr = jb * 16 + m15;
        bf16x8 vf = *(const bf16x8*)&Vs[cur][rr * 64 + ((s * 4 + q4) ^ (m15 & 7)) * 8];
        oa[jb] = MFMA16(pf, vf, oa[jb]);
      }
    }
    __syncthreads();
  }
#pragma unroll
  for (int jb = 0; jb < 4; jb++)
#pragma unroll
    for (int rg = 0; rg < 4; rg++) {
      int row = q0 + w * 16 + q4 * 4 + rg;
      int col = h * 64 + jb * 16 + m15;
      O[(size_t)row * 1024 + col] = __float2bfloat16(oa[jb][rg] / l_i[rg]);
    }
}

// ---------------- host ----------------
extern "C" void kernel_launch(void* const* d_in, const int* in_sizes, int n_in,
                              void* d_out, int out_size, void* d_ws, size_t ws_size,
                              hipStream_t stream) {
  (void)in_sizes; (void)n_in; (void)out_size; (void)ws_size;
  const float* vid  = (const float*)d_in[0];
  const float* act  = (const float*)d_in[1];
  const float* vfr  = (const float*)d_in[2];
  const float* afr  = (const float*)d_in[3];
  const float* tmv  = (const float*)d_in[4];
  const float* tma  = (const float*)d_in[5];
  const float* Wq   = (const float*)d_in[6];
  const float* Wk   = (const float*)d_in[7];
  const float* Wv   = (const float*)d_in[8];
  const float* Wo   = (const float*)d_in[9];
  const float* bq   = (const float*)d_in[10];
  const float* bk   = (const float*)d_in[11];
  const float* bv   = (const float*)d_in[12];
  const float* bo   = (const float*)d_in[13];
  const float* gq   = (const float*)d_in[14];
  const float* gk   = (const float*)d_in[15];
  const float* modp = (const float*)d_in[16];
  const float* W1   = (const float*)d_in[17];
  const float* b1   = (const float*)d_in[18];
  const float* W2   = (const float*)d_in[19];
  const float* b2   = (const float*)d_in[20];

  char* p = (char*)d_ws;
  auto carve = [&](size_t bytes) {
    char* r = p;
    p += (bytes + 255) & ~(size_t)255;
    return r;
  };
  BF16* WqT = (BF16*)carve(4ull * 1024 * 1024 * 2);
  BF16* WkT = (BF16*)carve(4ull * 1024 * 1024 * 2);
  BF16* WvT = (BF16*)carve(4ull * 1024 * 1024 * 2);
  BF16* WoT = (BF16*)carve(4ull * 1024 * 1024 * 2);
  BF16* W1T = (BF16*)carve(16ull * 1024 * 1024 * 2);
  BF16* W2T = (BF16*)carve(16ull * 1024 * 1024 * 2);
  float* x    = (float*)carve(2560ull * 1024 * 4);
  BF16* abf   = (BF16*)carve(2560ull * 1024 * 2);
  float* qraw = (float*)carve(2560ull * 1024 * 4);
  float* kraw = (float*)carve(2560ull * 1024 * 4);
  float* vraw = (float*)carve(2560ull * 1024 * 4);
  BF16* Qb    = (BF16*)carve(2560ull * 1024 * 2);
  BF16* Kb    = (BF16*)carve(2560ull * 1024 * 2);
  BF16* VTb   = (BF16*)carve(2560ull * 1024 * 2);
  BF16* Obf   = (BF16*)carve(2560ull * 1024 * 2);
  BF16* mibf  = (BF16*)carve(2560ull * 1024 * 2);
  BF16* hbf   = (BF16*)carve(2560ull * 4096 * 2);

  hipMemcpyAsync(x, vid, 2048ull * 1024 * 4, hipMemcpyDeviceToDevice, stream);
  hipMemcpyAsync(x + 2048ull * 1024, act, 512ull * 1024 * 4, hipMemcpyDeviceToDevice, stream);

  wtrans<<<dim3(32, 32, 4), 256, 0, stream>>>(Wq, WqT, 1024, 1024);
  wtrans<<<dim3(32, 32, 4), 256, 0, stream>>>(Wk, WkT, 1024, 1024);
  wtrans<<<dim3(32, 32, 4), 256, 0, stream>>>(Wv, WvT, 1024, 1024);
  wtrans<<<dim3(32, 32, 4), 256, 0, stream>>>(Wo, WoT, 1024, 1024);
  wtrans<<<dim3(128, 32, 4), 256, 0, stream>>>(W1, W1T, 1024, 4096);
  wtrans<<<dim3(32, 128, 4), 256, 0, stream>>>(W2, W2T, 4096, 1024);

  for (int l = 0; l < 2; l++) {
    ln_mod<<<2560, 256, 0, stream>>>(x, abf, modp, tmv, tma, l, 0, 1);
    {
      GPack<6> pk;
      for (int e = 0; e < 2; e++)
        for (int t = 0; t < 3; t++) {
          GDesc& dd = pk.d[e * 3 + t];
          dd.A = abf + (size_t)e * 2048 * 1024;
          dd.B = (t == 0 ? WqT : t == 1 ? WkT : WvT) + (size_t)(e * 2 + l) * 1024 * 1024;
          dd.bias = (t == 0 ? bq : t == 1 ? bk : bv) + (size_t)(e * 2 + l) * 1024;
          dd.out = (t == 0 ? qraw : t == 1 ? kraw : vraw) + (size_t)e * 2048 * 1024;
          dd.xin = nullptr; dd.xout = nullptr; dd.g1 = nullptr; dd.g2 = nullptr;
          dd.M = e ? 512 : 2048;
        }
      gemm_bt<0, 6><<<dim3(16, 8, 6), 256, 0, stream>>>(pk, 1024, 1024);
    }
    qk_post<<<dim3(2560, 2), 256, 0, stream>>>(qraw, kraw, gq, gk, Qb, Kb, vfr, afr, l);
    vpost<<<dim3(80, 32), 256, 0, stream>>>(vraw, VTb);
    flash<<<dim3(40, 16), 256, 0, stream>>>(Qb, Kb, VTb, Obf);
    {
      GPack<2> pk;
      for (int e = 0; e < 2; e++) {
        GDesc& dd = pk.d[e];
        dd.A = Obf + (size_t)e * 2048 * 1024;
        dd.B = WoT + (size_t)(e * 2 + l) * 1024 * 1024;
        dd.bias = bo + (size_t)(e * 2 + l) * 1024;
        dd.out = nullptr;
        dd.xin = x + (size_t)e * 2048 * 1024;
        dd.xout = x + (size_t)e * 2048 * 1024;
        dd.g1 = modp + (size_t)((e * 2 + l) * 6 + 2) * 1024;
        dd.g2 = (e ? tma : tmv) + 2 * 1024;
        dd.M = e ? 512 : 2048;
      }
      gemm_bt<2, 2><<<dim3(16, 8, 2), 256, 0, stream>>>(pk, 1024, 1024);
    }
    ln_mod<<<2560, 256, 0, stream>>>(x, mibf, modp, tmv, tma, l, 3, 4);
    {
      GPack<2> pk;
      for (int e = 0; e < 2; e++) {
        GDesc& dd = pk.d[e];
        dd.A = mibf + (size_t)e * 2048 * 1024;
        dd.B = W1T + (size_t)(e * 2 + l) * 4096 * 1024;
        dd.bias = b1 + (size_t)(e * 2 + l) * 4096;
        dd.out = hbf + (size_t)e * 2048 * 4096;
        dd.xin = nullptr; dd.xout = nullptr; dd.g1 = nullptr; dd.g2 = nullptr;
        dd.M = e ? 512 : 2048;
      }
      gemm_bt<1, 2><<<dim3(16, 32, 2), 256, 0, stream>>>(pk, 4096, 1024);
    }
    {
      GPack<2> pk;
      for (int e = 0; e < 2; e++) {
        GDesc& dd = pk.d[e];
        dd.A = hbf + (size_t)e * 2048 * 4096;
        dd.B = W2T + (size_t)(e * 2 + l) * 4096 * 1024;
        dd.bias = b2 + (size_t)(e * 2 + l) * 1024;
        dd.out = nullptr;
        dd.xin = x + (size_t)e * 2048 * 1024;
        dd.xout = ((l == 1) ? (float*)d_out : x) + (size_t)e * 2048 * 1024;
        dd.g1 = modp + (size_t)((e * 2 + l) * 6 + 5) * 1024;
        dd.g2 = (e ? tma : tmv) + 5 * 1024;
        dd.M = e ? 512 : 2048;
      }
      gemm_bt<2, 2><<<dim3(16, 8, 2), 256, 0, stream>>>(pk, 1024, 4096);
    }
  }
}

// Round 3
// 818.077 us; speedup vs baseline: 1.3366x; 1.2792x over previous
//
#include <hip/hip_runtime.h>
#include <hip/hip_bf16.h>

#define BF16 __hip_bfloat16
typedef short bf16x8 __attribute__((ext_vector_type(8)));
typedef float f32x4  __attribute__((ext_vector_type(4)));
typedef unsigned int u32;

#define MFMA16(a, b, c) __builtin_amdgcn_mfma_f32_16x16x32_bf16(a, b, c, 0, 0, 0)

// B=1, SV=2048, SA=512, S=2560, D=1024, H=16, DH=64, F=4096, L=2

__device__ __forceinline__ void async16(const void* g, void* l) {
  __builtin_amdgcn_global_load_lds(
      (const __attribute__((address_space(1))) u32*)g,
      (__attribute__((address_space(3))) u32*)l, 16, 0, 0);
}

__device__ __forceinline__ u32 pkbf(float a, float b) {
  union { BF16 h; unsigned short s; } ua, ub;
  ua.h = __float2bfloat16(a); ub.h = __float2bfloat16(b);
  return (u32)ua.s | ((u32)ub.s << 16);
}

// ---------------- weight transpose + f32->bf16 cast ----------------
// W: (nz, K, N) f32 -> WT: rows n, cols k bf16, out slab stride outZ
__global__ __launch_bounds__(256) void wtrans(const float* __restrict__ W,
                                              BF16* __restrict__ WT, int K, int N,
                                              size_t outZ) {
  __shared__ float t[32][33];
  const float* Wm = W + (size_t)K * N * blockIdx.z;
  BF16* Tm = WT + outZ * blockIdx.z;
  int n0 = blockIdx.x * 32, k0 = blockIdx.y * 32;
  int tx = threadIdx.x & 31, ty = threadIdx.x >> 5;
#pragma unroll
  for (int i = 0; i < 4; i++)
    t[ty + 8 * i][tx] = Wm[(size_t)(k0 + ty + 8 * i) * N + n0 + tx];
  __syncthreads();
#pragma unroll
  for (int i = 0; i < 4; i++)
    Tm[(size_t)(n0 + ty + 8 * i) * K + k0 + tx] = __float2bfloat16(t[tx][ty + 8 * i]);
}

// ---------------- fused qkv bias pack ----------------
__global__ __launch_bounds__(256) void packb(const float* __restrict__ bq,
                                             const float* __restrict__ bk,
                                             const float* __restrict__ bv,
                                             float* __restrict__ bqkv) {
  int i = blockIdx.x * 256 + threadIdx.x;  // 4*3072
  int s = i / 3072, c = i - s * 3072;
  float v = (c < 1024) ? bq[s * 1024 + c]
          : (c < 2048) ? bk[s * 1024 + c - 1024]
                       : bv[s * 1024 + c - 2048];
  bqkv[i] = v;
}

// ---------------- LayerNorm * (1+sc) + sh -> bf16 ----------------
__global__ __launch_bounds__(256) void ln_mod(const float* __restrict__ x,
                                              BF16* __restrict__ out,
                                              const float* __restrict__ mod,
                                              const float* __restrict__ tmv,
                                              const float* __restrict__ tma,
                                              int l, int ish, int isc) {
  int r = blockIdx.x;
  int e = (r >= 2048) ? 1 : 0;
  const float* tm = e ? tma : tmv;
  const float* mo = mod + (size_t)((e * 2 + l) * 6) * 1024;
  float4 v = ((const float4*)(x + (size_t)r * 1024))[threadIdx.x];
  float s = v.x + v.y + v.z + v.w;
  float s2 = v.x * v.x + v.y * v.y + v.z * v.z + v.w * v.w;
#pragma unroll
  for (int off = 32; off >= 1; off >>= 1) {
    s += __shfl_down(s, off);
    s2 += __shfl_down(s2, off);
  }
  __shared__ float red[8];
  int lane = threadIdx.x & 63, w = threadIdx.x >> 6;
  if (lane == 0) { red[w] = s; red[4 + w] = s2; }
  __syncthreads();
  s = red[0] + red[1] + red[2] + red[3];
  s2 = red[4] + red[5] + red[6] + red[7];
  float mu = s * (1.f / 1024.f);
  float var = s2 * (1.f / 1024.f) - mu * mu;
  float inv = rsqrtf(var + 1e-6f);
  int c = threadIdx.x * 4;
  BF16* o = out + (size_t)r * 1024 + c;
  float xv[4] = {v.x, v.y, v.z, v.w};
#pragma unroll
  for (int k = 0; k < 4; k++) {
    float sc = mo[isc * 1024 + c + k] + tm[isc * 1024 + c + k];
    float sh = mo[ish * 1024 + c + k] + tm[ish * 1024 + c + k];
    o[k] = __float2bfloat16((xv[k] - mu) * inv * (1.f + sc) + sh);
  }
}

// ---------------- RMSNorm + gain + RoPE, reads fused qkv (stride 3072) ----------------
__global__ __launch_bounds__(256) void qk_post(const float* __restrict__ qkv,
                                               const float* __restrict__ gq,
                                               const float* __restrict__ gk,
                                               BF16* __restrict__ Qb, BF16* __restrict__ Kb,
                                               const float* __restrict__ vfreq,
                                               const float* __restrict__ afreq, int l) {
  int r = blockIdx.x;
  int which = blockIdx.y;
  const float* src = qkv + (size_t)r * 3072 + which * 1024;
  int e = (r >= 2048) ? 1 : 0;
  const float* g = (which ? gk : gq) + (size_t)(e * 2 + l) * 1024;
  BF16* dst = which ? Kb : Qb;
  const float* fr = e ? (afreq + (size_t)(r - 2048) * 32) : (vfreq + (size_t)r * 32);
  float4 v = ((const float4*)src)[threadIdx.x];
  float s2 = v.x * v.x + v.y * v.y + v.z * v.z + v.w * v.w;
#pragma unroll
  for (int off = 32; off >= 1; off >>= 1) s2 += __shfl_down(s2, off);
  __shared__ float red[4];
  int lane = threadIdx.x & 63, w = threadIdx.x >> 6;
  if (lane == 0) red[w] = s2;
  __syncthreads();
  s2 = red[0] + red[1] + red[2] + red[3];
  float inv = rsqrtf(s2 * (1.f / 1024.f) + 1e-6f);
  int c = threadIdx.x * 4;
  float xe0 = v.x * inv * g[c], xo0 = v.y * inv * g[c + 1];
  float xe1 = v.z * inv * g[c + 2], xo1 = v.w * inv * g[c + 3];
  int p0 = (c & 63) >> 1;
  float c0, s0, c1, s1;
  __sincosf(fr[p0], &s0, &c0);
  __sincosf(fr[p0 + 1], &s1, &c1);
  int h = c >> 6;
  size_t o = ((size_t)h * 2560 + r) * 64 + (c & 63);
  dst[o + 0] = __float2bfloat16(xe0 * c0 - xo0 * s0);
  dst[o + 1] = __float2bfloat16(xe0 * s0 + xo0 * c0);
  dst[o + 2] = __float2bfloat16(xe1 * c1 - xo1 * s1);
  dst[o + 3] = __float2bfloat16(xe1 * s1 + xo1 * c1);
}

// ---------------- V (from qkv col 2048, stride 3072) -> V^T (H*DH, S) bf16 ----------------
__global__ __launch_bounds__(256) void vpost(const float* __restrict__ qkv,
                                             BF16* __restrict__ VT) {
  __shared__ float t[32][33];
  int r0 = blockIdx.x * 32, c0 = blockIdx.y * 32;
  int tx = threadIdx.x & 31, ty = threadIdx.x >> 5;
#pragma unroll
  for (int i = 0; i < 4; i++)
    t[ty + 8 * i][tx] = qkv[(size_t)(r0 + ty + 8 * i) * 3072 + 2048 + c0 + tx];
  __syncthreads();
#pragma unroll
  for (int i = 0; i < 4; i++)
    VT[(size_t)(c0 + ty + 8 * i) * 2560 + r0 + tx] = __float2bfloat16(t[tx][ty + 8 * i]);
}

// ---------------- GEMM v2: C = A(2560xK) * B^T(NxK), expert-aware, BK=64 ----------------
// EPI: 0 = f32 out + bias, 1 = gelu->bf16 + bias, 3 = f32 partial (split-K), no bias
template <int EPI, int KS>
__global__ __launch_bounds__(256) void gemm2(const BF16* __restrict__ A,
                                             const BF16* __restrict__ Bw, size_t Bestride,
                                             const float* __restrict__ bias, int biasE,
                                             void* __restrict__ out, float* __restrict__ part,
                                             int N, int K) {
  __shared__ BF16 As[128 * 64];
  __shared__ BF16 Bs[128 * 64];
  int flat = blockIdx.x + blockIdx.y * gridDim.x;
  int xcd = flat & 7, slot = flat >> 3;
  int bx = slot % gridDim.x;
  int by = (slot / gridDim.x) * 8 + xcd;  // gridDim.y % 8 == 0 for all launches
  int m0 = bx * 128, n0 = by * 128;
  int e = (m0 >= 2048);
  const BF16* Ab = A + (size_t)m0 * K;
  const BF16* Bb = Bw + (e ? Bestride : 0) + (size_t)n0 * K;
  int kz0 = blockIdx.z * (K / KS), kz1 = kz0 + K / KS;
  int tid = threadIdx.x, lane = tid & 63, w = tid >> 6;
  int wr = w & 1, wc = w >> 1;
  int m15 = lane & 15, q4 = lane >> 4;
  int L[4], rS[4], cS[4];
#pragma unroll
  for (int i = 0; i < 4; i++) {
    L[i] = w * 256 + i * 64 + lane;
    rS[i] = L[i] >> 3;
    cS[i] = (L[i] & 7) ^ (rS[i] & 7);
  }
  f32x4 acc[4][4] = {};
  for (int k0 = kz0; k0 < kz1; k0 += 64) {
    __syncthreads();
#pragma unroll
    for (int i = 0; i < 4; i++) {
      async16(Ab + (size_t)rS[i] * K + k0 + cS[i] * 8, &As[L[i] * 8]);
      async16(Bb + (size_t)rS[i] * K + k0 + cS[i] * 8, &Bs[L[i] * 8]);
    }
    __syncthreads();
#pragma unroll
    for (int kk = 0; kk < 2; kk++) {
      int pos = ((kk * 4 + q4) ^ (m15 & 7)) * 8;
      bf16x8 af[4], bv[4];
#pragma unroll
      for (int i = 0; i < 4; i++) af[i] = *(const bf16x8*)&As[(wr * 64 + i * 16 + m15) * 64 + pos];
#pragma unroll
      for (int j = 0; j < 4; j++) bv[j] = *(const bf16x8*)&Bs[(wc * 64 + j * 16 + m15) * 64 + pos];
#pragma unroll
      for (int i = 0; i < 4; i++)
#pragma unroll
        for (int j = 0; j < 4; j++)
          acc[i][j] = MFMA16(af[i], bv[j], acc[i][j]);
    }
  }
#pragma unroll
  for (int i = 0; i < 4; i++) {
    int row = m0 + wr * 64 + 16 * i + q4 * 4;
#pragma unroll
    for (int j = 0; j < 4; j++) {
      int col = n0 + wc * 64 + 16 * j + m15;
      float b = (EPI == 3) ? 0.f : bias[e * biasE + col];
#pragma unroll
      for (int rg = 0; rg < 4; rg++) {
        float v = acc[i][j][rg] + b;
        size_t idx = (size_t)(row + rg) * N + col;
        if (EPI == 0) {
          ((float*)out)[idx] = v;
        } else if (EPI == 1) {
          float u = 0.7978845608f * (v + 0.044715f * v * v * v);
          ((BF16*)out)[idx] = __float2bfloat16(0.5f * v * (1.f + tanhf(u)));
        } else {
          part[(size_t)blockIdx.z * 2560 * N + idx] = v;
        }
      }
    }
  }
}

// ---------------- split-K combine + gated residual: x' = xin + g*(sum part + bias) ----------------
template <int KS>
__global__ __launch_bounds__(256) void combine(const float* __restrict__ part,
                                               const float* __restrict__ biasL,
                                               const float* __restrict__ modp, int gi, int l,
                                               const float* __restrict__ tmv,
                                               const float* __restrict__ tma,
                                               const float* __restrict__ xin,
                                               float* __restrict__ xout) {
  int r = blockIdx.x, e = (r >= 2048) ? 1 : 0;
  int c = threadIdx.x * 4;
  float4 s = {0.f, 0.f, 0.f, 0.f};
#pragma unroll
  for (int z = 0; z < KS; z++) {
    float4 p = *(const float4*)&part[((size_t)z * 2560 + r) * 1024 + c];
    s.x += p.x; s.y += p.y; s.z += p.z; s.w += p.w;
  }
  float4 b = *(const float4*)&biasL[e * 2048 + c];
  const float* tm = e ? tma : tmv;
  float4 gm = *(const float4*)&modp[(size_t)((e * 2 + l) * 6 + gi) * 1024 + c];
  float4 gt = *(const float4*)&tm[gi * 1024 + c];
  float4 xi = *(const float4*)&xin[(size_t)r * 1024 + c];
  float4 o;
  o.x = xi.x + (gm.x + gt.x) * (s.x + b.x);
  o.y = xi.y + (gm.y + gt.y) * (s.y + b.y);
  o.z = xi.z + (gm.z + gt.z) * (s.z + b.z);
  o.w = xi.w + (gm.w + gt.w) * (s.w + b.w);
  *(float4*)&xout[(size_t)r * 1024 + c] = o;
}

// ---------------- flash attention v2: S^T formulation, KB=128, register P exchange ----------------
// Qb,Kb: (H,S,DH) bf16; VT: (H,DH,S) bf16; O: (S,1024) bf16
__global__ __launch_bounds__(256) void flash2(const BF16* __restrict__ Qb,
                                              const BF16* __restrict__ Kb,
                                              const BF16* __restrict__ VT,
                                              BF16* __restrict__ O) {
  const int S = 2560;
  __shared__ BF16 Ks[2][128 * 64];  // kv-major rows, 8 chunks/row, chunk c at c^(r&7)
  __shared__ BF16 Vs[2][64 * 128];  // dh-major rows, 16 chunks/row, chunk c at c^(r&15)
  int tid = threadIdx.x, lane = tid & 63, w = tid >> 6;
  int h = blockIdx.y, q0 = blockIdx.x * 64;
  int m15 = lane & 15, q4 = lane >> 4;
  int actq = (q0 >= 2048);
  int nt = actq ? ((q0 + 64 + 127) >> 7) : 16;
  // Q fragments direct from global (B-operand layout)
  const BF16* qrow = Qb + ((size_t)h * S + q0 + w * 16 + m15) * 64;
  bf16x8 qf0 = *(const bf16x8*)(qrow + q4 * 8);
  bf16x8 qf1 = *(const bf16x8*)(qrow + 32 + q4 * 8);
  const BF16* kbase = Kb + (size_t)h * S * 64;
  const BF16* vbase = VT + (size_t)h * 64 * S;
  int Lk[4], rK[4], cK[4], rV[4], cV[4];
#pragma unroll
  for (int i = 0; i < 4; i++) {
    Lk[i] = w * 256 + i * 64 + lane;
    rK[i] = Lk[i] >> 3; cK[i] = (Lk[i] & 7) ^ (rK[i] & 7);
    rV[i] = Lk[i] >> 4; cV[i] = (Lk[i] & 15) ^ (rV[i] & 15);
  }
  // stage tile 0
#pragma unroll
  for (int i = 0; i < 4; i++) {
    async16(kbase + (size_t)rK[i] * 64 + cK[i] * 8, &Ks[0][Lk[i] * 8]);
    async16(vbase + (size_t)rV[i] * S + cV[i] * 8, &Vs[0][Lk[i] * 8]);
  }
  f32x4 oa[4] = {};
  float m_i = -1e30f, l_i = 0.f;
  const float SC2 = 0.125f * 1.44269504f;
  int colq = q0 + w * 16 + m15;
  int sA = m15 + 16 * ((2 * q4) & 3);
  int sB = m15 + 16 * ((2 * q4 + 1) & 3);
  bool hi = (q4 >> 1) != 0;
  __syncthreads();
  for (int t = 0; t < nt; t++) {
    int cur = t & 1;
    if (t + 1 < nt) {
      int nb = cur ^ 1;
      const BF16* kg = kbase + (size_t)(t + 1) * 128 * 64;
      const BF16* vg = vbase + (size_t)(t + 1) * 128;
#pragma unroll
      for (int i = 0; i < 4; i++) {
        async16(kg + (size_t)rK[i] * 64 + cK[i] * 8, &Ks[nb][Lk[i] * 8]);
        async16(vg + (size_t)rV[i] * S + cV[i] * 8, &Vs[nb][Lk[i] * 8]);
      }
    }
    // S^T = K * Q^T : A-frag = K rows (kv), B-frag = Q
    f32x4 st[8];
#pragma unroll
    for (int jt = 0; jt < 8; jt++) {
      int row = jt * 16 + m15;
      bf16x8 kf0 = *(const bf16x8*)&Ks[cur][row * 64 + ((q4 ^ (m15 & 7))) * 8];
      bf16x8 kf1 = *(const bf16x8*)&Ks[cur][row * 64 + (((4 + q4) ^ (m15 & 7))) * 8];
      f32x4 z = {};
      z = MFMA16(kf0, qf0, z);
      st[jt] = MFMA16(kf1, qf1, z);
    }
    float sv[8][4];
    float mx = -1e30f;
    bool dom = actq && (t == nt - 1);
#pragma unroll
    for (int jt = 0; jt < 8; jt++)
#pragma unroll
      for (int rg = 0; rg < 4; rg++) {
        float vv = st[jt][rg] * SC2;
        if (dom) {
          int rowkv = t * 128 + jt * 16 + q4 * 4 + rg;
          if (rowkv > colq) vv = -1e30f;
        }
        sv[jt][rg] = vv;
        mx = fmaxf(mx, vv);
      }
    mx = fmaxf(mx, __shfl_xor(mx, 16));
    mx = fmaxf(mx, __shfl_xor(mx, 32));
    float mn = fmaxf(m_i, mx);
    float al = exp2f(m_i - mn);
    m_i = mn;
    float rs = 0.f;
    u32 pk[16];
#pragma unroll
    for (int jt = 0; jt < 8; jt++) {
      float p0 = exp2f(sv[jt][0] - mn), p1 = exp2f(sv[jt][1] - mn);
      float p2 = exp2f(sv[jt][2] - mn), p3 = exp2f(sv[jt][3] - mn);
      rs += (p0 + p1) + (p2 + p3);
      pk[jt * 2 + 0] = pkbf(p0, p1);
      pk[jt * 2 + 1] = pkbf(p2, p3);
    }
    rs += __shfl_xor(rs, 16);
    rs += __shfl_xor(rs, 32);
    l_i = l_i * al + rs;
#pragma unroll
    for (int dt = 0; dt < 4; dt++)
#pragma unroll
      for (int rg = 0; rg < 4; rg++) oa[dt][rg] *= al;
    // PV: O^T += V^T * P^T ; exchange P^T into B-operand layout via shuffles
#pragma unroll
    for (int kk = 0; kk < 4; kk++) {
      u32 a0 = __shfl((int)pk[4 * kk + 0], sA), c0_ = __shfl((int)pk[4 * kk + 2], sA);
      u32 a1 = __shfl((int)pk[4 * kk + 1], sA), c1_ = __shfl((int)pk[4 * kk + 3], sA);
      u32 b0 = __shfl((int)pk[4 * kk + 0], sB), d0 = __shfl((int)pk[4 * kk + 2], sB);
      u32 b1 = __shfl((int)pk[4 * kk + 1], sB), d1 = __shfl((int)pk[4 * kk + 3], sB);
      union { u32 u[4]; bf16x8 v; } pf;
      pf.u[0] = hi ? c0_ : a0;
      pf.u[1] = hi ? c1_ : a1;
      pf.u[2] = hi ? d0 : b0;
      pf.u[3] = hi ? d1 : b1;
#pragma unroll
      for (int dt = 0; dt < 4; dt++) {
        int vrow = dt * 16 + m15;
        bf16x8 vf = *(const bf16x8*)&Vs[cur][vrow * 128 + (((kk * 4 + q4) ^ m15)) * 8];
        oa[dt] = MFMA16(vf, pf.v, oa[dt]);
      }
    }
    __syncthreads();
  }
  float rl = 1.f / l_i;
  int orow = q0 + w * 16 + m15;
#pragma unroll
  for (int dt = 0; dt < 4; dt++) {
    int col = h * 64 + dt * 16 + q4 * 4;
    u32 lo = pkbf(oa[dt][0] * rl, oa[dt][1] * rl);
    u32 hi2 = pkbf(oa[dt][2] * rl, oa[dt][3] * rl);
    uint2 st2 = {lo, hi2};
    *(uint2*)&O[(size_t)orow * 1024 + col] = st2;
  }
}

// ---------------- host ----------------
extern "C" void kernel_launch(void* const* d_in, const int* in_sizes, int n_in,
                              void* d_out, int out_size, void* d_ws, size_t ws_size,
                              hipStream_t stream) {
  (void)in_sizes; (void)n_in; (void)out_size; (void)ws_size;
  const float* vid  = (const float*)d_in[0];
  const float* act  = (const float*)d_in[1];
  const float* vfr  = (const float*)d_in[2];
  const float* afr  = (const float*)d_in[3];
  const float* tmv  = (const float*)d_in[4];
  const float* tma  = (const float*)d_in[5];
  const float* Wq   = (const float*)d_in[6];
  const float* Wk   = (const float*)d_in[7];
  const float* Wv   = (const float*)d_in[8];
  const float* Wo   = (const float*)d_in[9];
  const float* bq   = (const float*)d_in[10];
  const float* bk   = (const float*)d_in[11];
  const float* bv   = (const float*)d_in[12];
  const float* bo   = (const float*)d_in[13];
  const float* gq   = (const float*)d_in[14];
  const float* gk   = (const float*)d_in[15];
  const float* modp = (const float*)d_in[16];
  const float* W1   = (const float*)d_in[17];
  const float* b1   = (const float*)d_in[18];
  const float* W2   = (const float*)d_in[19];
  const float* b2   = (const float*)d_in[20];

  char* p = (char*)d_ws;
  auto carve = [&](size_t bytes) {
    char* r = p;
    p += (bytes + 255) & ~(size_t)255;
    return r;
  };
  BF16* WqkvT = (BF16*)carve(4ull * 3072 * 1024 * 2);   // slabs (e*2+l): 3072 x 1024
  BF16* WoT   = (BF16*)carve(4ull * 1024 * 1024 * 2);
  BF16* W1T   = (BF16*)carve(4ull * 4096 * 1024 * 2);
  BF16* W2T   = (BF16*)carve(4ull * 1024 * 4096 * 2);
  float* bqkv = (float*)carve(4ull * 3072 * 4);
  float* x    = (float*)carve(2560ull * 1024 * 4);
  BF16* abf   = (BF16*)carve(2560ull * 1024 * 2);
  // part (4 x 2560 x 1024 f32) aliases [qkv, Qb, Kb] (exactly 41943040 bytes)
  float* qkv  = (float*)carve(2560ull * 3072 * 4);
  BF16* Qb    = (BF16*)carve(2560ull * 1024 * 2);
  BF16* Kb    = (BF16*)carve(2560ull * 1024 * 2);
  float* part = qkv;
  BF16* VTb   = (BF16*)carve(2560ull * 1024 * 2);
  BF16* Obf   = (BF16*)carve(2560ull * 1024 * 2);
  BF16* mibf  = (BF16*)carve(2560ull * 1024 * 2);
  BF16* hbf   = (BF16*)carve(2560ull * 4096 * 2);

  hipMemcpyAsync(x, vid, 2048ull * 1024 * 4, hipMemcpyDeviceToDevice, stream);
  hipMemcpyAsync(x + 2048ull * 1024, act, 512ull * 1024 * 4, hipMemcpyDeviceToDevice, stream);

  const size_t S3 = 3072ull * 1024;
  wtrans<<<dim3(32, 32, 4), 256, 0, stream>>>(Wq, WqkvT, 1024, 1024, S3);
  wtrans<<<dim3(32, 32, 4), 256, 0, stream>>>(Wk, WqkvT + 1024ull * 1024, 1024, 1024, S3);
  wtrans<<<dim3(32, 32, 4), 256, 0, stream>>>(Wv, WqkvT + 2048ull * 1024, 1024, 1024, S3);
  wtrans<<<dim3(32, 32, 4), 256, 0, stream>>>(Wo, WoT, 1024, 1024, 1024ull * 1024);
  wtrans<<<dim3(128, 32, 4), 256, 0, stream>>>(W1, W1T, 1024, 4096, 4096ull * 1024);
  wtrans<<<dim3(32, 128, 4), 256, 0, stream>>>(W2, W2T, 4096, 1024, 1024ull * 4096);
  packb<<<48, 256, 0, stream>>>(bq, bk, bv, bqkv);

  for (int l = 0; l < 2; l++) {
    ln_mod<<<2560, 256, 0, stream>>>(x, abf, modp, tmv, tma, l, 0, 1);
    // fused QKV: N=3072
    gemm2<0, 1><<<dim3(20, 24, 1), 256, 0, stream>>>(
        abf, WqkvT + (size_t)l * S3, 2 * S3, bqkv + l * 3072, 6144, qkv, nullptr, 3072, 1024);
    qk_post<<<dim3(2560, 2), 256, 0, stream>>>(qkv, gq, gk, Qb, Kb, vfr, afr, l);
    vpost<<<dim3(80, 32), 256, 0, stream>>>(qkv, VTb);
    flash2<<<dim3(40, 16), 256, 0, stream>>>(Qb, Kb, VTb, Obf);
    // Wo: split-K 2 -> partials (overwrites qkv/Qb/Kb which are now dead)
    gemm2<3, 2><<<dim3(20, 8, 2), 256, 0, stream>>>(
        Obf, WoT + (size_t)l * 1024 * 1024, 2ull * 1024 * 1024, nullptr, 0, nullptr, part,
        1024, 1024);
    combine<2><<<2560, 256, 0, stream>>>(part, bo + l * 1024, modp, 2, l, tmv, tma, x, x);
    ln_mod<<<2560, 256, 0, stream>>>(x, mibf, modp, tmv, tma, l, 3, 4);
    gemm2<1, 1><<<dim3(20, 32, 1), 256, 0, stream>>>(
        mibf, W1T + (size_t)l * 4096 * 1024, 2ull * 4096 * 1024, b1 + l * 4096, 8192, hbf,
        nullptr, 4096, 1024);
    gemm2<3, 4><<<dim3(20, 8, 4), 256, 0, stream>>>(
        hbf, W2T + (size_t)l * 4096 * 1024, 2ull * 4096 * 1024, nullptr, 0, nullptr, part,
        1024, 4096);
    combine<4><<<2560, 256, 0, stream>>>(part, b2 + l * 1024, modp, 5, l, tmv, tma, x,
                                         (l == 1) ? (float*)d_out : x);
  }
}

// Round 4
// 781.939 us; speedup vs baseline: 1.3984x; 1.0462x over previous
//
#include <hip/hip_runtime.h>
#include <hip/hip_bf16.h>

#define BF16 __hip_bfloat16
typedef short bf16x8 __attribute__((ext_vector_type(8)));
typedef float f32x4  __attribute__((ext_vector_type(4)));
typedef unsigned int u32;

#define MFMA16(a, b, c) __builtin_amdgcn_mfma_f32_16x16x32_bf16(a, b, c, 0, 0, 0)

// B=1, SV=2048, SA=512, S=2560, D=1024, H=16, DH=64, F=4096, L=2

__device__ __forceinline__ void async16(const void* g, void* l) {
  __builtin_amdgcn_global_load_lds(
      (const __attribute__((address_space(1))) u32*)g,
      (__attribute__((address_space(3))) u32*)l, 16, 0, 0);
}

__device__ __forceinline__ u32 pkbf(float a, float b) {
  union { BF16 h; unsigned short s; } ua, ub;
  ua.h = __float2bfloat16(a); ub.h = __float2bfloat16(b);
  return (u32)ua.s | ((u32)ub.s << 16);
}

// ---------------- weight transpose + f32->bf16 cast ----------------
__global__ __launch_bounds__(256) void wtrans(const float* __restrict__ W,
                                              BF16* __restrict__ WT, int K, int N,
                                              size_t outZ) {
  __shared__ float t[32][33];
  const float* Wm = W + (size_t)K * N * blockIdx.z;
  BF16* Tm = WT + outZ * blockIdx.z;
  int n0 = blockIdx.x * 32, k0 = blockIdx.y * 32;
  int tx = threadIdx.x & 31, ty = threadIdx.x >> 5;
#pragma unroll
  for (int i = 0; i < 4; i++)
    t[ty + 8 * i][tx] = Wm[(size_t)(k0 + ty + 8 * i) * N + n0 + tx];
  __syncthreads();
#pragma unroll
  for (int i = 0; i < 4; i++)
    Tm[(size_t)(n0 + ty + 8 * i) * K + k0 + tx] = __float2bfloat16(t[tx][ty + 8 * i]);
}

// ---------------- fused qkv bias pack ----------------
__global__ __launch_bounds__(256) void packb(const float* __restrict__ bq,
                                             const float* __restrict__ bk,
                                             const float* __restrict__ bv,
                                             float* __restrict__ bqkv) {
  int i = blockIdx.x * 256 + threadIdx.x;  // 4*3072
  int s = i / 3072, c = i - s * 3072;
  float v = (c < 1024) ? bq[s * 1024 + c]
          : (c < 2048) ? bk[s * 1024 + c - 1024]
                       : bv[s * 1024 + c - 2048];
  bqkv[i] = v;
}

// ---------------- LayerNorm * (1+sc) + sh -> bf16 ----------------
__global__ __launch_bounds__(256) void ln_mod(const float* __restrict__ x,
                                              BF16* __restrict__ out,
                                              const float* __restrict__ mod,
                                              const float* __restrict__ tmv,
                                              const float* __restrict__ tma,
                                              int l, int ish, int isc) {
  int r = blockIdx.x;
  int e = (r >= 2048) ? 1 : 0;
  const float* tm = e ? tma : tmv;
  const float* mo = mod + (size_t)((e * 2 + l) * 6) * 1024;
  float4 v = ((const float4*)(x + (size_t)r * 1024))[threadIdx.x];
  float s = v.x + v.y + v.z + v.w;
  float s2 = v.x * v.x + v.y * v.y + v.z * v.z + v.w * v.w;
#pragma unroll
  for (int off = 32; off >= 1; off >>= 1) {
    s += __shfl_down(s, off);
    s2 += __shfl_down(s2, off);
  }
  __shared__ float red[8];
  int lane = threadIdx.x & 63, w = threadIdx.x >> 6;
  if (lane == 0) { red[w] = s; red[4 + w] = s2; }
  __syncthreads();
  s = red[0] + red[1] + red[2] + red[3];
  s2 = red[4] + red[5] + red[6] + red[7];
  float mu = s * (1.f / 1024.f);
  float var = s2 * (1.f / 1024.f) - mu * mu;
  float inv = rsqrtf(var + 1e-6f);
  int c = threadIdx.x * 4;
  BF16* o = out + (size_t)r * 1024 + c;
  float xv[4] = {v.x, v.y, v.z, v.w};
#pragma unroll
  for (int k = 0; k < 4; k++) {
    float sc = mo[isc * 1024 + c + k] + tm[isc * 1024 + c + k];
    float sh = mo[ish * 1024 + c + k] + tm[ish * 1024 + c + k];
    o[k] = __float2bfloat16((xv[k] - mu) * inv * (1.f + sc) + sh);
  }
}

// ---------------- RMSNorm + gain + RoPE, reads fused qkv (stride 3072) ----------------
// Q rows are pre-scaled by 0.125*log2(e) so flash uses exp2 with raw dot products.
__global__ __launch_bounds__(256) void qk_post(const float* __restrict__ qkv,
                                               const float* __restrict__ gq,
                                               const float* __restrict__ gk,
                                               BF16* __restrict__ Qb, BF16* __restrict__ Kb,
                                               const float* __restrict__ vfreq,
                                               const float* __restrict__ afreq, int l) {
  int r = blockIdx.x;
  int which = blockIdx.y;
  const float* src = qkv + (size_t)r * 3072 + which * 1024;
  int e = (r >= 2048) ? 1 : 0;
  const float* g = (which ? gk : gq) + (size_t)(e * 2 + l) * 1024;
  BF16* dst = which ? Kb : Qb;
  const float* fr = e ? (afreq + (size_t)(r - 2048) * 32) : (vfreq + (size_t)r * 32);
  float4 v = ((const float4*)src)[threadIdx.x];
  float s2 = v.x * v.x + v.y * v.y + v.z * v.z + v.w * v.w;
#pragma unroll
  for (int off = 32; off >= 1; off >>= 1) s2 += __shfl_down(s2, off);
  __shared__ float red[4];
  int lane = threadIdx.x & 63, w = threadIdx.x >> 6;
  if (lane == 0) red[w] = s2;
  __syncthreads();
  s2 = red[0] + red[1] + red[2] + red[3];
  float inv = rsqrtf(s2 * (1.f / 1024.f) + 1e-6f);
  if (which == 0) inv *= 0.125f * 1.44269504f;  // fold softmax scale into Q
  int c = threadIdx.x * 4;
  float xe0 = v.x * inv * g[c], xo0 = v.y * inv * g[c + 1];
  float xe1 = v.z * inv * g[c + 2], xo1 = v.w * inv * g[c + 3];
  int p0 = (c & 63) >> 1;
  float c0, s0, c1, s1;
  __sincosf(fr[p0], &s0, &c0);
  __sincosf(fr[p0 + 1], &s1, &c1);
  int h = c >> 6;
  size_t o = ((size_t)h * 2560 + r) * 64 + (c & 63);
  dst[o + 0] = __float2bfloat16(xe0 * c0 - xo0 * s0);
  dst[o + 1] = __float2bfloat16(xe0 * s0 + xo0 * c0);
  dst[o + 2] = __float2bfloat16(xe1 * c1 - xo1 * s1);
  dst[o + 3] = __float2bfloat16(xe1 * s1 + xo1 * c1);
}

// ---------------- V (from qkv col 2048, stride 3072) -> V^T (H*DH, S) bf16 ----------------
__global__ __launch_bounds__(256) void vpost(const float* __restrict__ qkv,
                                             BF16* __restrict__ VT) {
  __shared__ float t[32][33];
  int r0 = blockIdx.x * 32, c0 = blockIdx.y * 32;
  int tx = threadIdx.x & 31, ty = threadIdx.x >> 5;
#pragma unroll
  for (int i = 0; i < 4; i++)
    t[ty + 8 * i][tx] = qkv[(size_t)(r0 + ty + 8 * i) * 3072 + 2048 + c0 + tx];
  __syncthreads();
#pragma unroll
  for (int i = 0; i < 4; i++)
    VT[(size_t)(c0 + ty + 8 * i) * 2560 + r0 + tx] = __float2bfloat16(t[tx][ty + 8 * i]);
}

// ---------------- GEMM v2: C = A(2560xK) * B^T(NxK), expert-aware, BK=64 ----------------
template <int EPI, int KS>
__global__ __launch_bounds__(256) void gemm2(const BF16* __restrict__ A,
                                             const BF16* __restrict__ Bw, size_t Bestride,
                                             const float* __restrict__ bias, int biasE,
                                             void* __restrict__ out, float* __restrict__ part,
                                             int N, int K) {
  __shared__ BF16 As[128 * 64];
  __shared__ BF16 Bs[128 * 64];
  int flat = blockIdx.x + blockIdx.y * gridDim.x;
  int xcd = flat & 7, slot = flat >> 3;
  int bx = slot % gridDim.x;
  int by = (slot / gridDim.x) * 8 + xcd;
  int m0 = bx * 128, n0 = by * 128;
  int e = (m0 >= 2048);
  const BF16* Ab = A + (size_t)m0 * K;
  const BF16* Bb = Bw + (e ? Bestride : 0) + (size_t)n0 * K;
  int kz0 = blockIdx.z * (K / KS), kz1 = kz0 + K / KS;
  int tid = threadIdx.x, lane = tid & 63, w = tid >> 6;
  int wr = w & 1, wc = w >> 1;
  int m15 = lane & 15, q4 = lane >> 4;
  int L[4], rS[4], cS[4];
#pragma unroll
  for (int i = 0; i < 4; i++) {
    L[i] = w * 256 + i * 64 + lane;
    rS[i] = L[i] >> 3;
    cS[i] = (L[i] & 7) ^ (rS[i] & 7);
  }
  f32x4 acc[4][4] = {};
  for (int k0 = kz0; k0 < kz1; k0 += 64) {
    __syncthreads();
#pragma unroll
    for (int i = 0; i < 4; i++) {
      async16(Ab + (size_t)rS[i] * K + k0 + cS[i] * 8, &As[L[i] * 8]);
      async16(Bb + (size_t)rS[i] * K + k0 + cS[i] * 8, &Bs[L[i] * 8]);
    }
    __syncthreads();
#pragma unroll
    for (int kk = 0; kk < 2; kk++) {
      int pos = ((kk * 4 + q4) ^ (m15 & 7)) * 8;
      bf16x8 af[4], bv[4];
#pragma unroll
      for (int i = 0; i < 4; i++) af[i] = *(const bf16x8*)&As[(wr * 64 + i * 16 + m15) * 64 + pos];
#pragma unroll
      for (int j = 0; j < 4; j++) bv[j] = *(const bf16x8*)&Bs[(wc * 64 + j * 16 + m15) * 64 + pos];
#pragma unroll
      for (int i = 0; i < 4; i++)
#pragma unroll
        for (int j = 0; j < 4; j++)
          acc[i][j] = MFMA16(af[i], bv[j], acc[i][j]);
    }
  }
#pragma unroll
  for (int i = 0; i < 4; i++) {
    int row = m0 + wr * 64 + 16 * i + q4 * 4;
#pragma unroll
    for (int j = 0; j < 4; j++) {
      int col = n0 + wc * 64 + 16 * j + m15;
      float b = (EPI == 3) ? 0.f : bias[e * biasE + col];
#pragma unroll
      for (int rg = 0; rg < 4; rg++) {
        float v = acc[i][j][rg] + b;
        size_t idx = (size_t)(row + rg) * N + col;
        if (EPI == 0) {
          ((float*)out)[idx] = v;
        } else if (EPI == 1) {
          float u = 0.7978845608f * (v + 0.044715f * v * v * v);
          ((BF16*)out)[idx] = __float2bfloat16(0.5f * v * (1.f + tanhf(u)));
        } else {
          part[(size_t)blockIdx.z * 2560 * N + idx] = v;
        }
      }
    }
  }
}

// ---------------- split-K combine + gated residual ----------------
template <int KS>
__global__ __launch_bounds__(256) void combine(const float* __restrict__ part,
                                               const float* __restrict__ biasL,
                                               const float* __restrict__ modp, int gi, int l,
                                               const float* __restrict__ tmv,
                                               const float* __restrict__ tma,
                                               const float* __restrict__ xin,
                                               float* __restrict__ xout) {
  int r = blockIdx.x, e = (r >= 2048) ? 1 : 0;
  int c = threadIdx.x * 4;
  float4 s = {0.f, 0.f, 0.f, 0.f};
#pragma unroll
  for (int z = 0; z < KS; z++) {
    float4 p = *(const float4*)&part[((size_t)z * 2560 + r) * 1024 + c];
    s.x += p.x; s.y += p.y; s.z += p.z; s.w += p.w;
  }
  float4 b = *(const float4*)&biasL[e * 2048 + c];
  const float* tm = e ? tma : tmv;
  float4 gm = *(const float4*)&modp[(size_t)((e * 2 + l) * 6 + gi) * 1024 + c];
  float4 gt = *(const float4*)&tm[gi * 1024 + c];
  float4 xi = *(const float4*)&xin[(size_t)r * 1024 + c];
  float4 o;
  o.x = xi.x + (gm.x + gt.x) * (s.x + b.x);
  o.y = xi.y + (gm.y + gt.y) * (s.y + b.y);
  o.z = xi.z + (gm.z + gt.z) * (s.z + b.z);
  o.w = xi.w + (gm.w + gt.w) * (s.w + b.w);
  *(float4*)&xout[(size_t)r * 1024 + c] = o;
}

// ---------------- flash v3: S^T = K·Q^T, O = P·V, P via wave-private LDS ----------------
// Qb (pre-scaled),Kb: (H,S,DH) bf16; VT: (H,DH,S) bf16; O: (S,1024) bf16
// KB=64 tiles; LDS ~41KB -> 3 blocks/CU.
__global__ __launch_bounds__(256) void flash3(const BF16* __restrict__ Qb,
                                              const BF16* __restrict__ Kb,
                                              const BF16* __restrict__ VT,
                                              BF16* __restrict__ O) {
  const int S = 2560;
  __shared__ BF16 Ks[2][64 * 64];
  __shared__ BF16 Vs[2][64 * 64];
  __shared__ BF16 Ps[4][16 * 72];  // wave-private P (q-major, stride 72)
  int tid = threadIdx.x, lane = tid & 63, w = tid >> 6;
  int h = blockIdx.y, q0 = blockIdx.x * 64;
  int m15 = lane & 15, q4 = lane >> 4;
  int actq = (q0 >= 2048);
  int nt = actq ? ((q0 >> 6) + 1) : 32;
  const BF16* qrow = Qb + ((size_t)h * S + q0 + w * 16 + m15) * 64;
  bf16x8 qf0 = *(const bf16x8*)(qrow + q4 * 8);
  bf16x8 qf1 = *(const bf16x8*)(qrow + 32 + q4 * 8);
  const BF16* kbase = Kb + (size_t)h * S * 64;
  const BF16* vbase = VT + (size_t)h * 64 * S;
  // staging: 64x64 tile = 512 chunks; 2 per thread
  int L0 = w * 128 + lane, L1 = L0 + 64;
  int r0 = L0 >> 3, c0 = (L0 & 7) ^ (r0 & 7);
  int r1 = L1 >> 3, c1 = (L1 & 7) ^ (r1 & 7);
  async16(kbase + (size_t)r0 * 64 + c0 * 8, &Ks[0][L0 * 8]);
  async16(kbase + (size_t)r1 * 64 + c1 * 8, &Ks[0][L1 * 8]);
  async16(vbase + (size_t)r0 * S + c0 * 8, &Vs[0][L0 * 8]);
  async16(vbase + (size_t)r1 * S + c1 * 8, &Vs[0][L1 * 8]);
  f32x4 oa[4] = {};
  float m_i = -1e30f, l_i = 0.f;
  int colq = q0 + w * 16 + m15;
  BF16* Pw = &Ps[w][0];
  int x0 = (q4 ^ (m15 & 7)) * 8, x1 = ((4 + q4) ^ (m15 & 7)) * 8;
  __syncthreads();
  for (int t = 0; t < nt; t++) {
    int cur = t & 1;
    if (t + 1 < nt) {
      int nb = cur ^ 1;
      const BF16* kg = kbase + (size_t)(t + 1) * 64 * 64;
      const BF16* vg = vbase + (size_t)(t + 1) * 64;
      async16(kg + (size_t)r0 * 64 + c0 * 8, &Ks[nb][L0 * 8]);
      async16(kg + (size_t)r1 * 64 + c1 * 8, &Ks[nb][L1 * 8]);
      async16(vg + (size_t)r0 * S + c0 * 8, &Vs[nb][L0 * 8]);
      async16(vg + (size_t)r1 * S + c1 * 8, &Vs[nb][L1 * 8]);
    }
    // S^T = K * Q^T (col = q = m15, row = kv)
    f32x4 st[4];
#pragma unroll
    for (int jt = 0; jt < 4; jt++) {
      int row = (jt * 16 + m15) * 64;
      bf16x8 kf0 = *(const bf16x8*)&Ks[cur][row + x0];
      bf16x8 kf1 = *(const bf16x8*)&Ks[cur][row + x1];
      f32x4 z = {};
      z = MFMA16(kf0, qf0, z);
      st[jt] = MFMA16(kf1, qf1, z);
    }
    float mx = -1e30f;
    if (actq && t == nt - 1) {
#pragma unroll
      for (int jt = 0; jt < 4; jt++)
#pragma unroll
        for (int rg = 0; rg < 4; rg++) {
          int rowkv = t * 64 + jt * 16 + q4 * 4 + rg;
          if (rowkv > colq) st[jt][rg] = -1e30f;
          mx = fmaxf(mx, st[jt][rg]);
        }
    } else {
#pragma unroll
      for (int jt = 0; jt < 4; jt++)
        mx = fmaxf(fmaxf(fmaxf(mx, st[jt][0]), fmaxf(st[jt][1], st[jt][2])), st[jt][3]);
    }
    mx = fmaxf(mx, __shfl_xor(mx, 16));
    mx = fmaxf(mx, __shfl_xor(mx, 32));
    float mn = fmaxf(m_i, mx);
    float al = exp2f(m_i - mn);
    m_i = mn;
    float rs = 0.f;
#pragma unroll
    for (int jt = 0; jt < 4; jt++) {
      float p0 = exp2f(st[jt][0] - mn), p1 = exp2f(st[jt][1] - mn);
      float p2 = exp2f(st[jt][2] - mn), p3 = exp2f(st[jt][3] - mn);
      rs += (p0 + p1) + (p2 + p3);
      uint2 pr = {pkbf(p0, p1), pkbf(p2, p3)};
      *(uint2*)&Pw[m15 * 72 + jt * 16 + q4 * 4] = pr;  // P[q][kv], b64
    }
    rs += __shfl_xor(rs, 16);
    rs += __shfl_xor(rs, 32);
    l_i = l_i * al + rs;
    float alr[4];
#pragma unroll
    for (int rg = 0; rg < 4; rg++) alr[rg] = __shfl(al, q4 * 4 + rg);
#pragma unroll
    for (int dt = 0; dt < 4; dt++)
#pragma unroll
      for (int rg = 0; rg < 4; rg++) oa[dt][rg] *= alr[rg];
    // O += P * V  (A = P from wave-private LDS, B = V^T rows)
    bf16x8 pf0 = *(const bf16x8*)&Pw[m15 * 72 + q4 * 8];
    bf16x8 pf1 = *(const bf16x8*)&Pw[m15 * 72 + 32 + q4 * 8];
#pragma unroll
    for (int dt = 0; dt < 4; dt++) {
      int vr = (dt * 16 + m15) * 64;
      bf16x8 vf0 = *(const bf16x8*)&Vs[cur][vr + x0];
      bf16x8 vf1 = *(const bf16x8*)&Vs[cur][vr + x1];
      oa[dt] = MFMA16(pf0, vf0, oa[dt]);
      oa[dt] = MFMA16(pf1, vf1, oa[dt]);
    }
    __syncthreads();
  }
  float rl = 1.f / l_i;
  float rlr[4];
#pragma unroll
  for (int rg = 0; rg < 4; rg++) rlr[rg] = __shfl(rl, q4 * 4 + rg);
#pragma unroll
  for (int dt = 0; dt < 4; dt++)
#pragma unroll
    for (int rg = 0; rg < 4; rg++) {
      int row = q0 + w * 16 + q4 * 4 + rg;
      int col = h * 64 + dt * 16 + m15;
      O[(size_t)row * 1024 + col] = __float2bfloat16(oa[dt][rg] * rlr[rg]);
    }
}

// ---------------- host ----------------
extern "C" void kernel_launch(void* const* d_in, const int* in_sizes, int n_in,
                              void* d_out, int out_size, void* d_ws, size_t ws_size,
                              hipStream_t stream) {
  (void)in_sizes; (void)n_in; (void)out_size; (void)ws_size;
  const float* vid  = (const float*)d_in[0];
  const float* act  = (const float*)d_in[1];
  const float* vfr  = (const float*)d_in[2];
  const float* afr  = (const float*)d_in[3];
  const float* tmv  = (const float*)d_in[4];
  const float* tma  = (const float*)d_in[5];
  const float* Wq   = (const float*)d_in[6];
  const float* Wk   = (const float*)d_in[7];
  const float* Wv   = (const float*)d_in[8];
  const float* Wo   = (const float*)d_in[9];
  const float* bq   = (const float*)d_in[10];
  const float* bk   = (const float*)d_in[11];
  const float* bv   = (const float*)d_in[12];
  const float* bo   = (const float*)d_in[13];
  const float* gq   = (const float*)d_in[14];
  const float* gk   = (const float*)d_in[15];
  const float* modp = (const float*)d_in[16];
  const float* W1   = (const float*)d_in[17];
  const float* b1   = (const float*)d_in[18];
  const float* W2   = (const float*)d_in[19];
  const float* b2   = (const float*)d_in[20];

  char* p = (char*)d_ws;
  auto carve = [&](size_t bytes) {
    char* r = p;
    p += (bytes + 255) & ~(size_t)255;
    return r;
  };
  BF16* WqkvT = (BF16*)carve(4ull * 3072 * 1024 * 2);
  BF16* WoT   = (BF16*)carve(4ull * 1024 * 1024 * 2);
  BF16* W1T   = (BF16*)carve(4ull * 4096 * 1024 * 2);
  BF16* W2T   = (BF16*)carve(4ull * 1024 * 4096 * 2);
  float* bqkv = (float*)carve(4ull * 3072 * 4);
  float* x    = (float*)carve(2560ull * 1024 * 4);
  BF16* abf   = (BF16*)carve(2560ull * 1024 * 2);
  float* qkv  = (float*)carve(2560ull * 3072 * 4);
  BF16* Qb    = (BF16*)carve(2560ull * 1024 * 2);
  BF16* Kb    = (BF16*)carve(2560ull * 1024 * 2);
  float* part = qkv;  // aliases qkv/Qb/Kb region (dead when partials are live)
  BF16* VTb   = (BF16*)carve(2560ull * 1024 * 2);
  BF16* Obf   = (BF16*)carve(2560ull * 1024 * 2);
  BF16* mibf  = (BF16*)carve(2560ull * 1024 * 2);
  BF16* hbf   = (BF16*)carve(2560ull * 4096 * 2);

  hipMemcpyAsync(x, vid, 2048ull * 1024 * 4, hipMemcpyDeviceToDevice, stream);
  hipMemcpyAsync(x + 2048ull * 1024, act, 512ull * 1024 * 4, hipMemcpyDeviceToDevice, stream);

  const size_t S3 = 3072ull * 1024;
  wtrans<<<dim3(32, 32, 4), 256, 0, stream>>>(Wq, WqkvT, 1024, 1024, S3);
  wtrans<<<dim3(32, 32, 4), 256, 0, stream>>>(Wk, WqkvT + 1024ull * 1024, 1024, 1024, S3);
  wtrans<<<dim3(32, 32, 4), 256, 0, stream>>>(Wv, WqkvT + 2048ull * 1024, 1024, 1024, S3);
  wtrans<<<dim3(32, 32, 4), 256, 0, stream>>>(Wo, WoT, 1024, 1024, 1024ull * 1024);
  wtrans<<<dim3(128, 32, 4), 256, 0, stream>>>(W1, W1T, 1024, 4096, 4096ull * 1024);
  wtrans<<<dim3(32, 128, 4), 256, 0, stream>>>(W2, W2T, 4096, 1024, 1024ull * 4096);
  packb<<<48, 256, 0, stream>>>(bq, bk, bv, bqkv);

  for (int l = 0; l < 2; l++) {
    ln_mod<<<2560, 256, 0, stream>>>(x, abf, modp, tmv, tma, l, 0, 1);
    gemm2<0, 1><<<dim3(20, 24, 1), 256, 0, stream>>>(
        abf, WqkvT + (size_t)l * S3, 2 * S3, bqkv + l * 3072, 6144, qkv, nullptr, 3072, 1024);
    qk_post<<<dim3(2560, 2), 256, 0, stream>>>(qkv, gq, gk, Qb, Kb, vfr, afr, l);
    vpost<<<dim3(80, 32), 256, 0, stream>>>(qkv, VTb);
    flash3<<<dim3(40, 16), 256, 0, stream>>>(Qb, Kb, VTb, Obf);
    gemm2<3, 2><<<dim3(20, 8, 2), 256, 0, stream>>>(
        Obf, WoT + (size_t)l * 1024 * 1024, 2ull * 1024 * 1024, nullptr, 0, nullptr, part,
        1024, 1024);
    combine<2><<<2560, 256, 0, stream>>>(part, bo + l * 1024, modp, 2, l, tmv, tma, x, x);
    ln_mod<<<2560, 256, 0, stream>>>(x, mibf, modp, tmv, tma, l, 3, 4);
    gemm2<1, 1><<<dim3(20, 32, 1), 256, 0, stream>>>(
        mibf, W1T + (size_t)l * 4096 * 1024, 2ull * 4096 * 1024, b1 + l * 4096, 8192, hbf,
        nullptr, 4096, 1024);
    gemm2<3, 4><<<dim3(20, 8, 4), 256, 0, stream>>>(
        hbf, W2T + (size_t)l * 4096 * 1024, 2ull * 4096 * 1024, nullptr, 0, nullptr, part,
        1024, 4096);
    combine<4><<<2560, 256, 0, stream>>>(part, b2 + l * 1024, modp, 5, l, tmv, tma, x,
                                         (l == 1) ? (float*)d_out : x);
  }
}